// Round 1
// baseline (13410.452 us; speedup 1.0000x reference)
//
#include <hip/hip_runtime.h>
#include <math.h>

namespace {
constexpr int Bc = 2, Tc = 1024, Dc = 1024, Hc = 16, Fc = 2730;
constexpr int DHc = 64;
constexpr int Mc = Bc * Tc;               // 2048 rows
constexpr float EPSc = 1e-6f;
constexpr float NEGc = -10000.0f;
constexpr float SCALEc = 0.125f;          // 1/sqrt(64)
}

// ---------------- embedding gather ----------------
__global__ void k_embed(const int* __restrict__ ids, const float* __restrict__ ew,
                        float* __restrict__ x) {
    int row = blockIdx.x;                 // 0..2047
    int id = ids[row];
    const float4* src = (const float4*)(ew + (size_t)id * Dc);
    float4* dst = (float4*)(x + (size_t)row * Dc);
    dst[threadIdx.x] = src[threadIdx.x];  // 256 threads * 4 floats = 1024
}

// ---------------- me_norm: out = x / (mean|x| + eps) * w ----------------
__global__ void k_menorm(const float* __restrict__ x, const float* __restrict__ w,
                         float* __restrict__ out) {
    int row = blockIdx.x;
    const float4* xr = (const float4*)(x + (size_t)row * Dc);
    float4 v = xr[threadIdx.x];
    float s = fabsf(v.x) + fabsf(v.y) + fabsf(v.z) + fabsf(v.w);
#pragma unroll
    for (int m = 32; m >= 1; m >>= 1) s += __shfl_xor(s, m);
    __shared__ float ws4[4];
    if ((threadIdx.x & 63) == 0) ws4[threadIdx.x >> 6] = s;
    __syncthreads();
    float tot = ws4[0] + ws4[1] + ws4[2] + ws4[3];
    float inv = 1.0f / (tot / (float)Dc + EPSc);
    const float4* wr = (const float4*)w;
    float4 wv = wr[threadIdx.x];
    float4 o;
    o.x = v.x * inv * wv.x;
    o.y = v.y * inv * wv.y;
    o.z = v.z * inv * wv.z;
    o.w = v.w * inv * wv.w;
    ((float4*)(out + (size_t)row * Dc))[threadIdx.x] = o;
}

// ---------------- GEMM: C[m,n] = sum_k A[m,k]*B[n,k] (+ Res[m,n]) ----------------
// A: (M,K) row-major; B: (N,K) row-major (i.e. computes A @ B^T). M % 64 == 0.
template <bool ADD_RES>
__global__ __launch_bounds__(256) void k_gemm_abt(
    const float* __restrict__ A, const float* __restrict__ Bm,
    const float* __restrict__ Res, float* __restrict__ C,
    int M, int N, int K) {
    __shared__ float As[64][17];
    __shared__ float Bs[64][17];
    int tx = threadIdx.x % 16, ty = threadIdx.x / 16;
    int bm = blockIdx.y * 64, bn = blockIdx.x * 64;
    float acc[4][4] = {};
    int lr = threadIdx.x / 4;             // 0..63
    int lc = (threadIdx.x % 4) * 4;       // 0,4,8,12

    for (int k0 = 0; k0 < K; k0 += 16) {
        int gm = bm + lr;
        int gn = bn + lr;
#pragma unroll
        for (int j = 0; j < 4; j++) {
            int gk = k0 + lc + j;
            As[lr][lc + j] = (gk < K) ? A[(size_t)gm * K + gk] : 0.0f;
            Bs[lr][lc + j] = (gn < N && gk < K) ? Bm[(size_t)gn * K + gk] : 0.0f;
        }
        __syncthreads();
#pragma unroll
        for (int kk = 0; kk < 16; kk++) {
            float a[4], b[4];
#pragma unroll
            for (int i = 0; i < 4; i++) a[i] = As[ty * 4 + i][kk];
#pragma unroll
            for (int j = 0; j < 4; j++) b[j] = Bs[tx * 4 + j][kk];
#pragma unroll
            for (int i = 0; i < 4; i++)
#pragma unroll
                for (int j = 0; j < 4; j++) acc[i][j] += a[i] * b[j];
        }
        __syncthreads();
    }
#pragma unroll
    for (int i = 0; i < 4; i++) {
        int gm = bm + ty * 4 + i;
#pragma unroll
        for (int j = 0; j < 4; j++) {
            int gn = bn + tx * 4 + j;
            if (gn < N) {
                size_t idx = (size_t)gm * N + gn;
                float v = acc[i][j];
                if (ADD_RES) v += Res[idx];
                C[idx] = v;
            }
        }
    }
}

// ---------------- attention: per block = one (b,h) and 8 query rows ----------------
// qkv layout: [b][t][c][h][dh], row stride 3*D. Writes o in (B,T,H*DH) layout.
__global__ __launch_bounds__(256) void k_attn(const float* __restrict__ qkv,
                                              float* __restrict__ o) {
    constexpr int R = 8;
    int t0 = blockIdx.x * R;
    int h = blockIdx.y;
    int b = blockIdx.z;
    float slope = exp2f(-0.5f * (float)(h + 1));

    __shared__ float sc[R][Tc];           // 32 KB scores
    __shared__ float qs[R][DHc];          // 2 KB
    __shared__ float kv[64][DHc + 1];     // 16.25 KB K/V tile
    __shared__ float rowsum[R];

    // load Q rows
    for (int i = threadIdx.x; i < R * DHc; i += 256) {
        int r = i / DHc, dh = i % DHc;
        qs[r][dh] = qkv[(size_t)(b * Tc + t0 + r) * (3 * Dc) + 0 * Dc + h * DHc + dh];
    }

    int ls = threadIdx.x % 32;            // 32 threads per row
    int rr = threadIdx.x / 32;            // row 0..7

    // ---- scores ----
    for (int st = 0; st < Tc; st += 64) {
        __syncthreads();
        for (int i = threadIdx.x; i < 64 * DHc; i += 256) {
            int s = i / DHc, dh = i % DHc;
            kv[s][dh] = qkv[(size_t)(b * Tc + st + s) * (3 * Dc) + 1 * Dc + h * DHc + dh];
        }
        __syncthreads();
#pragma unroll
        for (int half = 0; half < 2; half++) {
            int sl = half * 32 + ls;
            int s = st + sl;
            int t = t0 + rr;
            float scv;
            if (s > t) {
                scv = NEGc;
            } else {
                float dot = 0.0f;
#pragma unroll
                for (int d = 0; d < DHc; d++) dot += qs[rr][d] * kv[sl][d];
                scv = dot * SCALEc - slope * fabsf((float)(t - s));
            }
            sc[rr][s] = scv;
        }
    }
    __syncthreads();

    // ---- row max ----
    float mx = -INFINITY;
    for (int s = ls; s < Tc; s += 32) mx = fmaxf(mx, sc[rr][s]);
#pragma unroll
    for (int m = 16; m >= 1; m >>= 1) mx = fmaxf(mx, __shfl_xor(mx, m));

    // ---- rational numerator + row sum ----
    float sum = 0.0f;
    for (int s = ls; s < Tc; s += 32) {
        float sv = sc[rr][s] - mx;
        float num = 1.0f / (1.0f - sv + 0.5f * sv * sv);
        sc[rr][s] = num;
        sum += num;
    }
#pragma unroll
    for (int m = 16; m >= 1; m >>= 1) sum += __shfl_xor(sum, m);
    if (ls == 0) rowsum[rr] = sum;

    // ---- PV ----
    int d = threadIdx.x % 64;
    int rg = threadIdx.x / 64;            // 0..3 -> rows rg and rg+4
    float acc0 = 0.0f, acc1 = 0.0f;
    for (int st = 0; st < Tc; st += 64) {
        __syncthreads();
        for (int i = threadIdx.x; i < 64 * DHc; i += 256) {
            int s = i / DHc, dh = i % DHc;
            kv[s][dh] = qkv[(size_t)(b * Tc + st + s) * (3 * Dc) + 2 * Dc + h * DHc + dh];
        }
        __syncthreads();
#pragma unroll 8
        for (int sl = 0; sl < 64; sl++) {
            float vv = kv[sl][d];
            acc0 += sc[rg][st + sl] * vv;
            acc1 += sc[rg + 4][st + sl] * vv;
        }
    }
    __syncthreads();
    {
        int r = rg;
        o[(size_t)(b * Tc + t0 + r) * Dc + h * DHc + d] = acc0 / (rowsum[r] + EPSc);
        r = rg + 4;
        o[(size_t)(b * Tc + t0 + r) * Dc + h * DHc + d] = acc1 / (rowsum[r] + EPSc);
    }
}

// ---------------- gated FFN elementwise: g = gate*sigma*val ----------------
__global__ void k_gate(const float* __restrict__ gv, float* __restrict__ g) {
    int m = blockIdx.y;
    for (int f = blockIdx.x * 256 + threadIdx.x; f < Fc; f += gridDim.x * 256) {
        float gate = gv[(size_t)m * (2 * Fc) + f];
        float val = gv[(size_t)m * (2 * Fc) + Fc + f];
        float sigma = 0.5f * (gate / (fabsf(gate) + 1.0f) + 1.0f);
        g[(size_t)m * Fc + f] = gate * sigma * val;
    }
}

extern "C" void kernel_launch(void* const* d_in, const int* in_sizes, int n_in,
                              void* d_out, int out_size, void* d_ws, size_t ws_size,
                              hipStream_t stream) {
    const int* ids = (const int*)d_in[0];
    const float* embed_w = (const float*)d_in[1];
    const float* qkv_w = (const float*)d_in[2];
    const float* out_w = (const float*)d_in[3];
    const float* gate_w = (const float*)d_in[4];
    const float* wout_w = (const float*)d_in[5];
    const float* n1 = (const float*)d_in[6];
    const float* n2 = (const float*)d_in[7];
    const float* nf = (const float*)d_in[8];
    float* outp = (float*)d_out;

    char* ws = (char*)d_ws;
    float* x = (float*)(ws + 0);                         // 8 MB
    float* h = (float*)(ws + (size_t)8 * 1024 * 1024);   // 8 MB
    float* o = (float*)(ws + (size_t)16 * 1024 * 1024);  // 8 MB
    float* qkv = (float*)(ws + (size_t)24 * 1024 * 1024);  // shared region
    float* gv = qkv;                                       // 44.7 MB (gv is max user)
    float* g = (float*)(ws + (size_t)24 * 1024 * 1024 + (size_t)44728320);  // 22.4 MB

    dim3 blk(256);

    k_embed<<<dim3(Mc), blk, 0, stream>>>(ids, embed_w, x);

    for (int l = 0; l < 4; l++) {
        const float* wq = qkv_w + (size_t)l * 3 * Dc * Dc;
        const float* wo = out_w + (size_t)l * Dc * Dc;
        const float* wg = gate_w + (size_t)l * 2 * Fc * Dc;
        const float* ww = wout_w + (size_t)l * Dc * Fc;

        // h = me_norm(x, n1)
        k_menorm<<<dim3(Mc), blk, 0, stream>>>(x, n1 + (size_t)l * Dc, h);
        // qkv = h @ wq^T   (M=2048, N=3072, K=1024)
        k_gemm_abt<false><<<dim3(48, 32), blk, 0, stream>>>(h, wq, nullptr, qkv, Mc, 3 * Dc, Dc);
        // attention -> o in (B,T,D)
        k_attn<<<dim3(Tc / 8, Hc, Bc), blk, 0, stream>>>(qkv, o);
        // x = x + o @ wo^T  (N=1024, K=1024)
        k_gemm_abt<true><<<dim3(16, 32), blk, 0, stream>>>(o, wo, x, x, Mc, Dc, Dc);
        // h = me_norm(x, n2)
        k_menorm<<<dim3(Mc), blk, 0, stream>>>(x, n2 + (size_t)l * Dc, h);
        // gv = h @ wg^T  (N=5460, K=1024)
        k_gemm_abt<false><<<dim3(86, 32), blk, 0, stream>>>(h, wg, nullptr, gv, Mc, 2 * Fc, Dc);
        // g = gate*sigma*val
        k_gate<<<dim3(11, Mc), blk, 0, stream>>>(gv, g);
        // x = x + g @ ww^T  (N=1024, K=2730)
        k_gemm_abt<true><<<dim3(16, 32), blk, 0, stream>>>(g, ww, x, x, Mc, Dc, Fc);
    }

    // final norm + logits
    k_menorm<<<dim3(Mc), blk, 0, stream>>>(x, nf, h);
    // logits = h @ embed_w^T  (N=32000, K=1024)
    k_gemm_abt<false><<<dim3(500, 32), blk, 0, stream>>>(h, embed_w, nullptr, outp, Mc, 32000, Dc);
}

// Round 3
// 2874.536 us; speedup vs baseline: 4.6653x; 4.6653x over previous
//
#include <hip/hip_runtime.h>
#include <math.h>

typedef __attribute__((ext_vector_type(8))) short bf16x8;
typedef __attribute__((ext_vector_type(4))) float f32x4;

namespace {
constexpr int Bc = 2, Tc = 1024, Dc = 1024, Hc = 16, Fc = 2730;
constexpr int Fp = 2752;   // padded F (K of wout GEMM)
constexpr int Gp = 5504;   // padded 2F (N of gate GEMM)
constexpr int DHc = 64;
constexpr int Mc = Bc * Tc;               // 2048 rows
constexpr float EPSc = 1e-6f;
constexpr float NEGc = -10000.0f;
constexpr float SCALEc = 0.125f;          // 1/sqrt(64)
}

// fp32 -> bf16 RTNE (finite values only, which holds here)
__device__ __forceinline__ unsigned short f2b(float f) {
    unsigned int u = __float_as_uint(f);
    u += 0x7FFFu + ((u >> 16) & 1u);
    return (unsigned short)(u >> 16);
}

// ---------------- embedding gather (fp32 x) ----------------
__global__ void k_embed(const int* __restrict__ ids, const float* __restrict__ ew,
                        float* __restrict__ x) {
    int row = blockIdx.x;
    int id = ids[row];
    const float4* src = (const float4*)(ew + (size_t)id * Dc);
    float4* dst = (float4*)(x + (size_t)row * Dc);
    dst[threadIdx.x] = src[threadIdx.x];
}

// ---------------- straight fp32 -> bf16 convert, n % 1024 == 0, grid = n/1024 ----------------
__global__ void k_conv(const float* __restrict__ in, unsigned short* __restrict__ out) {
    size_t i = ((size_t)blockIdx.x * 256 + threadIdx.x) * 4;
    float4 v = *(const float4*)(in + i);
    ushort4 o;
    o.x = f2b(v.x); o.y = f2b(v.y); o.z = f2b(v.z); o.w = f2b(v.w);
    *(ushort4*)(out + i) = o;
}

// ---------------- gate weight convert with row pad: out [Gp][1024], rows >= validRows zero ----------------
__global__ void k_conv_padrows(const float* __restrict__ in, unsigned short* __restrict__ out,
                               int validRows) {
    int r = blockIdx.x;                   // 0..Gp-1
    int c = threadIdx.x * 4;              // 1024 cols / 4 = 256 threads
    ushort4 o;
    if (r < validRows) {
        float4 v = *(const float4*)(in + (size_t)r * Dc + c);
        o.x = f2b(v.x); o.y = f2b(v.y); o.z = f2b(v.z); o.w = f2b(v.w);
    } else {
        o.x = o.y = o.z = o.w = 0;
    }
    *(ushort4*)(out + (size_t)r * Dc + c) = o;
}

// ---------------- wout weight convert with col pad: in [1024][Fc] -> out [1024][Fp] ----------------
__global__ void k_conv_padk(const float* __restrict__ in, unsigned short* __restrict__ out) {
    int r = blockIdx.x;                   // 0..1023
    for (int c = threadIdx.x; c < Fp; c += 256) {
        float v = (c < Fc) ? in[(size_t)r * Fc + c] : 0.0f;
        out[(size_t)r * Fp + c] = f2b(v);
    }
}

// ---------------- me_norm -> bf16 out ----------------
__global__ void k_menorm_b(const float* __restrict__ x, const float* __restrict__ w,
                           unsigned short* __restrict__ out) {
    int row = blockIdx.x;
    float4 v = ((const float4*)(x + (size_t)row * Dc))[threadIdx.x];
    float s = fabsf(v.x) + fabsf(v.y) + fabsf(v.z) + fabsf(v.w);
#pragma unroll
    for (int m = 32; m >= 1; m >>= 1) s += __shfl_xor(s, m);
    __shared__ float ws4[4];
    if ((threadIdx.x & 63) == 0) ws4[threadIdx.x >> 6] = s;
    __syncthreads();
    float tot = ws4[0] + ws4[1] + ws4[2] + ws4[3];
    float inv = 1.0f / (tot / (float)Dc + EPSc);
    float4 wv = ((const float4*)w)[threadIdx.x];
    ushort4 o;
    o.x = f2b(v.x * inv * wv.x);
    o.y = f2b(v.y * inv * wv.y);
    o.z = f2b(v.z * inv * wv.z);
    o.w = f2b(v.w * inv * wv.w);
    ((ushort4*)(out + (size_t)row * Dc))[threadIdx.x] = o;
}

// ---------------- MFMA GEMM: C[m,n] = sum_k A[m,k]*B[n,k] (+ Res) ----------------
// A: [M][K] bf16, B: [N][K] bf16, C/Res fp32 [M][N]. M,N % 128 == 0, K % 64 == 0.
// m97 structure: 128x128 tile, BK=64, 4 waves, global_load_lds w=16, XOR chunk swizzle.
template <bool ADD_RES>
__global__ __launch_bounds__(256) void k_mfma_gemm(
    const unsigned short* __restrict__ A, const unsigned short* __restrict__ Bw,
    const float* __restrict__ Res, float* __restrict__ C, int N, int K) {
    __shared__ __align__(16) unsigned short As[128 * 64];
    __shared__ __align__(16) unsigned short Bs[128 * 64];
    const int tid = threadIdx.x;
    const int lane = tid & 63;
    const int wid = tid >> 6;
    const int wr = wid >> 1, wc = wid & 1;
    const int bm = blockIdx.y * 128, bn = blockIdx.x * 128;

    f32x4 acc[4][4] = {};

    const int nk = K >> 6;
    for (int kt = 0; kt < nk; ++kt) {
        const int k0 = kt << 6;
        // stage A,B tiles: 1024 chunks of 16B each; chunk ci at LDS offset ci*16,
        // sourced from global chunk (row r = ci>>3, col (ci&7) ^ (r&7))  [swizzle]
#pragma unroll
        for (int it = 0; it < 4; ++it) {
            int ci = it * 256 + tid;
            int r = ci >> 3;
            int sc = (ci & 7) ^ (r & 7);
            __builtin_amdgcn_global_load_lds(
                (const __attribute__((address_space(1))) void*)(A + (size_t)(bm + r) * K + k0 + sc * 8),
                (__attribute__((address_space(3))) void*)(As + ci * 8), 16, 0, 0);
            __builtin_amdgcn_global_load_lds(
                (const __attribute__((address_space(1))) void*)(Bw + (size_t)(bn + r) * K + k0 + sc * 8),
                (__attribute__((address_space(3))) void*)(Bs + ci * 8), 16, 0, 0);
        }
        __syncthreads();
#pragma unroll
        for (int kk = 0; kk < 2; ++kk) {
            bf16x8 af[4], bfr[4];
            const int kc = kk * 4 + (lane >> 4);   // 16B-chunk column 0..7
#pragma unroll
            for (int m = 0; m < 4; ++m) {
                int row = wr * 64 + m * 16 + (lane & 15);
                af[m] = *(const bf16x8*)&As[(row * 8 + (kc ^ (row & 7))) * 8];
            }
#pragma unroll
            for (int n = 0; n < 4; ++n) {
                int col = wc * 64 + n * 16 + (lane & 15);
                bfr[n] = *(const bf16x8*)&Bs[(col * 8 + (kc ^ (col & 7))) * 8];
            }
#pragma unroll
            for (int m = 0; m < 4; ++m)
#pragma unroll
                for (int n = 0; n < 4; ++n)
                    acc[m][n] = __builtin_amdgcn_mfma_f32_16x16x32_bf16(af[m], bfr[n], acc[m][n], 0, 0, 0);
        }
        __syncthreads();
    }
    // epilogue: C/D mapping col = lane&15, row = (lane>>4)*4 + j  [m89-verified]
#pragma unroll
    for (int m = 0; m < 4; ++m) {
        int row0 = bm + wr * 64 + m * 16 + ((lane >> 4) << 2);
#pragma unroll
        for (int n = 0; n < 4; ++n) {
            int col = bn + wc * 64 + n * 16 + (lane & 15);
#pragma unroll
            for (int j = 0; j < 4; ++j) {
                size_t idx = (size_t)(row0 + j) * N + col;
                float v = acc[m][n][j];
                if (ADD_RES) v += Res[idx];
                C[idx] = v;
            }
        }
    }
}

// ---------------- attention (fp32 compute, bf16 out): block = (b,h,8 q-rows) ----------------
__global__ __launch_bounds__(256) void k_attn(const float* __restrict__ qkv,
                                              unsigned short* __restrict__ o) {
    constexpr int R = 8;
    int t0 = blockIdx.x * R;
    int h = blockIdx.y;
    int b = blockIdx.z;
    float slope = exp2f(-0.5f * (float)(h + 1));

    __shared__ float sc[R][Tc];
    __shared__ float qs[R][DHc];
    __shared__ float kv[64][DHc + 1];
    __shared__ float rowsum[R];

    for (int i = threadIdx.x; i < R * DHc; i += 256) {
        int r = i / DHc, dh = i % DHc;
        qs[r][dh] = qkv[(size_t)(b * Tc + t0 + r) * (3 * Dc) + h * DHc + dh];
    }

    int ls = threadIdx.x % 32;
    int rr = threadIdx.x / 32;

    for (int st = 0; st < Tc; st += 64) {
        __syncthreads();
        for (int i = threadIdx.x; i < 64 * DHc; i += 256) {
            int s = i / DHc, dh = i % DHc;
            kv[s][dh] = qkv[(size_t)(b * Tc + st + s) * (3 * Dc) + Dc + h * DHc + dh];
        }
        __syncthreads();
#pragma unroll
        for (int half = 0; half < 2; half++) {
            int sl = half * 32 + ls;
            int s = st + sl;
            int t = t0 + rr;
            float scv;
            if (s > t) {
                scv = NEGc;
            } else {
                float dot = 0.0f;
#pragma unroll
                for (int d = 0; d < DHc; d++) dot += qs[rr][d] * kv[sl][d];
                scv = dot * SCALEc - slope * fabsf((float)(t - s));
            }
            sc[rr][s] = scv;
        }
    }
    __syncthreads();

    float mx = -INFINITY;
    for (int s = ls; s < Tc; s += 32) mx = fmaxf(mx, sc[rr][s]);
#pragma unroll
    for (int m = 16; m >= 1; m >>= 1) mx = fmaxf(mx, __shfl_xor(mx, m));

    float sum = 0.0f;
    for (int s = ls; s < Tc; s += 32) {
        float sv = sc[rr][s] - mx;
        float num = 1.0f / (1.0f - sv + 0.5f * sv * sv);
        sc[rr][s] = num;
        sum += num;
    }
#pragma unroll
    for (int m = 16; m >= 1; m >>= 1) sum += __shfl_xor(sum, m);
    if (ls == 0) rowsum[rr] = sum;

    int d = threadIdx.x % 64;
    int rg = threadIdx.x / 64;
    float acc0 = 0.0f, acc1 = 0.0f;
    for (int st = 0; st < Tc; st += 64) {
        __syncthreads();
        for (int i = threadIdx.x; i < 64 * DHc; i += 256) {
            int s = i / DHc, dh = i % DHc;
            kv[s][dh] = qkv[(size_t)(b * Tc + st + s) * (3 * Dc) + 2 * Dc + h * DHc + dh];
        }
        __syncthreads();
#pragma unroll 8
        for (int sl = 0; sl < 64; sl++) {
            float vv = kv[sl][d];
            acc0 += sc[rg][st + sl] * vv;
            acc1 += sc[rg + 4][st + sl] * vv;
        }
    }
    __syncthreads();
    {
        int r = rg;
        o[(size_t)(b * Tc + t0 + r) * Dc + h * DHc + d] = f2b(acc0 / (rowsum[r] + EPSc));
        r = rg + 4;
        o[(size_t)(b * Tc + t0 + r) * Dc + h * DHc + d] = f2b(acc1 / (rowsum[r] + EPSc));
    }
}

// ---------------- gate elementwise: g[m][k<Fp] = gate*sigma*val (bf16, zero-padded K) ----------------
__global__ void k_gate(const float* __restrict__ gv, unsigned short* __restrict__ g) {
    int m = blockIdx.y;
    int f = blockIdx.x * 256 + threadIdx.x;
    if (f >= Fp) return;
    unsigned short out = 0;
    if (f < Fc) {
        float gate = gv[(size_t)m * Gp + f];
        float val = gv[(size_t)m * Gp + Fc + f];
        float sigma = 0.5f * (gate / (fabsf(gate) + 1.0f) + 1.0f);
        out = f2b(gate * sigma * val);
    }
    g[(size_t)m * Fp + f] = out;
}

extern "C" void kernel_launch(void* const* d_in, const int* in_sizes, int n_in,
                              void* d_out, int out_size, void* d_ws, size_t ws_size,
                              hipStream_t stream) {
    const int* ids = (const int*)d_in[0];
    const float* embed_w = (const float*)d_in[1];
    const float* qkv_w = (const float*)d_in[2];
    const float* out_w = (const float*)d_in[3];
    const float* gate_w = (const float*)d_in[4];
    const float* wout_w = (const float*)d_in[5];
    const float* n1 = (const float*)d_in[6];
    const float* n2 = (const float*)d_in[7];
    const float* nf = (const float*)d_in[8];
    float* outp = (float*)d_out;

    char* ws = (char*)d_ws;
    // layout (bytes):
    float* x = (float*)(ws + 0);                                   //  8,388,608
    unsigned short* h = (unsigned short*)(ws + 8388608);           //  4,194,304 (h / o share)
    float* qkv = (float*)(ws + 12582912);                          // 45,088,768 (qkv / gv share)
    float* gv = qkv;
    unsigned short* g = (unsigned short*)(ws + 57671680);          // 11,272,192
    unsigned short* w1 = (unsigned short*)(ws + 68943872);         //  6,291,456 (wq / ww share)
    unsigned short* wo_b = (unsigned short*)(ws + 75235328);       //  2,097,152
    unsigned short* wg_b = (unsigned short*)(ws + 77332480);       // 11,272,192  (end 88,604,672)
    unsigned short* emb_b = (unsigned short*)(ws + 12582912);      // 65,536,000 (overlays dead bufs at end)

    dim3 blk(256);

    k_embed<<<dim3(Mc), blk, 0, stream>>>(ids, embed_w, x);

    for (int l = 0; l < 4; l++) {
        const float* wq = qkv_w + (size_t)l * 3 * Dc * Dc;
        const float* wo = out_w + (size_t)l * Dc * Dc;
        const float* wg = gate_w + (size_t)l * 2 * Fc * Dc;
        const float* ww = wout_w + (size_t)l * Dc * Fc;

        k_conv<<<dim3(3072), blk, 0, stream>>>(wq, w1);
        k_conv<<<dim3(1024), blk, 0, stream>>>(wo, wo_b);
        k_conv_padrows<<<dim3(Gp), blk, 0, stream>>>(wg, wg_b, 2 * Fc);

        // h = me_norm(x, n1) -> bf16
        k_menorm_b<<<dim3(Mc), blk, 0, stream>>>(x, n1 + (size_t)l * Dc, h);
        // qkv = h @ wq^T   (N=3072, K=1024)
        k_mfma_gemm<false><<<dim3(24, 16), blk, 0, stream>>>(h, w1, nullptr, qkv, 3 * Dc, Dc);
        // ww -> w1 (wq no longer needed)
        k_conv_padk<<<dim3(1024), blk, 0, stream>>>(ww, w1);
        // attention -> o (reuses h buffer, bf16)
        k_attn<<<dim3(Tc / 8, Hc, Bc), blk, 0, stream>>>(qkv, h);
        // x = x + o @ wo^T  (N=1024, K=1024)
        k_mfma_gemm<true><<<dim3(8, 16), blk, 0, stream>>>(h, wo_b, x, x, Dc, Dc);
        // h = me_norm(x, n2)
        k_menorm_b<<<dim3(Mc), blk, 0, stream>>>(x, n2 + (size_t)l * Dc, h);
        // gv = h @ wg^T  (N=5504 padded, K=1024)
        k_mfma_gemm<false><<<dim3(Gp / 128, 16), blk, 0, stream>>>(h, wg_b, nullptr, gv, Gp, Dc);
        // g = gate*sigma*val -> bf16, K padded to 2752
        k_gate<<<dim3((Fp + 255) / 256, Mc), blk, 0, stream>>>(gv, g);
        // x = x + g @ ww^T  (N=1024, K=2752 padded)
        k_mfma_gemm<true><<<dim3(8, 16), blk, 0, stream>>>(g, w1, x, x, Dc, Fp);
    }

    // final norm + logits
    k_menorm_b<<<dim3(Mc), blk, 0, stream>>>(x, nf, h);
    k_conv<<<dim3(32000), blk, 0, stream>>>(embed_w, emb_b);
    // logits = h @ embed^T  (N=32000, K=1024)
    k_mfma_gemm<false><<<dim3(250, 16), blk, 0, stream>>>(h, emb_b, nullptr, outp, 32000, Dc);
}

// Round 4
// 1231.751 us; speedup vs baseline: 10.8873x; 2.3337x over previous
//
#include <hip/hip_runtime.h>
#include <math.h>

typedef __attribute__((ext_vector_type(8))) short bf16x8;
typedef __attribute__((ext_vector_type(4))) float f32x4;

namespace {
constexpr int Bc = 2, Tc = 1024, Dc = 1024, Hc = 16, Fc = 2730;
constexpr int Fp = 2752;   // padded F (K of wout GEMM)
constexpr int Gp = 5504;   // padded 2F (N of gate GEMM)
constexpr int Mc = Bc * Tc;               // 2048 rows
constexpr float EPSc = 1e-6f;
constexpr float NEGc = -10000.0f;
constexpr float SCALEc = 0.125f;          // 1/sqrt(64)
}

// fp32 -> bf16 RTNE (finite values only, which holds here)
__device__ __forceinline__ unsigned short f2b(float f) {
    unsigned int u = __float_as_uint(f);
    u += 0x7FFFu + ((u >> 16) & 1u);
    return (unsigned short)(u >> 16);
}

// ---------------- embedding gather (fp32 x) ----------------
__global__ void k_embed(const int* __restrict__ ids, const float* __restrict__ ew,
                        float* __restrict__ x) {
    int row = blockIdx.x;
    int id = ids[row];
    const float4* src = (const float4*)(ew + (size_t)id * Dc);
    float4* dst = (float4*)(x + (size_t)row * Dc);
    dst[threadIdx.x] = src[threadIdx.x];
}

// ---------------- straight fp32 -> bf16 convert, n % 1024 == 0, grid = n/1024 ----------------
__global__ void k_conv(const float* __restrict__ in, unsigned short* __restrict__ out) {
    size_t i = ((size_t)blockIdx.x * 256 + threadIdx.x) * 4;
    float4 v = *(const float4*)(in + i);
    ushort4 o;
    o.x = f2b(v.x); o.y = f2b(v.y); o.z = f2b(v.z); o.w = f2b(v.w);
    *(ushort4*)(out + i) = o;
}

// ---------------- gate weight convert with row pad ----------------
__global__ void k_conv_padrows(const float* __restrict__ in, unsigned short* __restrict__ out,
                               int validRows) {
    int r = blockIdx.x;
    int c = threadIdx.x * 4;
    ushort4 o;
    if (r < validRows) {
        float4 v = *(const float4*)(in + (size_t)r * Dc + c);
        o.x = f2b(v.x); o.y = f2b(v.y); o.z = f2b(v.z); o.w = f2b(v.w);
    } else {
        o.x = o.y = o.z = o.w = 0;
    }
    *(ushort4*)(out + (size_t)r * Dc + c) = o;
}

// ---------------- wout weight convert with col pad: [1024][Fc] -> [1024][Fp] ----------------
__global__ void k_conv_padk(const float* __restrict__ in, unsigned short* __restrict__ out) {
    int r = blockIdx.x;
    for (int c = threadIdx.x; c < Fp; c += 256) {
        float v = (c < Fc) ? in[(size_t)r * Fc + c] : 0.0f;
        out[(size_t)r * Fp + c] = f2b(v);
    }
}

// ---------------- me_norm -> bf16 out ----------------
__global__ void k_menorm_b(const float* __restrict__ x, const float* __restrict__ w,
                           unsigned short* __restrict__ out) {
    int row = blockIdx.x;
    float4 v = ((const float4*)(x + (size_t)row * Dc))[threadIdx.x];
    float s = fabsf(v.x) + fabsf(v.y) + fabsf(v.z) + fabsf(v.w);
#pragma unroll
    for (int m = 32; m >= 1; m >>= 1) s += __shfl_xor(s, m);
    __shared__ float ws4[4];
    if ((threadIdx.x & 63) == 0) ws4[threadIdx.x >> 6] = s;
    __syncthreads();
    float tot = ws4[0] + ws4[1] + ws4[2] + ws4[3];
    float inv = 1.0f / (tot / (float)Dc + EPSc);
    float4 wv = ((const float4*)w)[threadIdx.x];
    ushort4 o;
    o.x = f2b(v.x * inv * wv.x);
    o.y = f2b(v.y * inv * wv.y);
    o.z = f2b(v.z * inv * wv.z);
    o.w = f2b(v.w * inv * wv.w);
    ((ushort4*)(out + (size_t)row * Dc))[threadIdx.x] = o;
}

// ---------------- MFMA GEMM (m97 structure), unchanged from round 3 ----------------
template <bool ADD_RES>
__global__ __launch_bounds__(256) void k_mfma_gemm(
    const unsigned short* __restrict__ A, const unsigned short* __restrict__ Bw,
    const float* __restrict__ Res, float* __restrict__ C, int N, int K) {
    __shared__ __align__(16) unsigned short As[128 * 64];
    __shared__ __align__(16) unsigned short Bs[128 * 64];
    const int tid = threadIdx.x;
    const int lane = tid & 63;
    const int wid = tid >> 6;
    const int wr = wid >> 1, wc = wid & 1;
    const int bm = blockIdx.y * 128, bn = blockIdx.x * 128;

    f32x4 acc[4][4] = {};

    const int nk = K >> 6;
    for (int kt = 0; kt < nk; ++kt) {
        const int k0 = kt << 6;
#pragma unroll
        for (int it = 0; it < 4; ++it) {
            int ci = it * 256 + tid;
            int r = ci >> 3;
            int sc = (ci & 7) ^ (r & 7);
            __builtin_amdgcn_global_load_lds(
                (const __attribute__((address_space(1))) void*)(A + (size_t)(bm + r) * K + k0 + sc * 8),
                (__attribute__((address_space(3))) void*)(As + ci * 8), 16, 0, 0);
            __builtin_amdgcn_global_load_lds(
                (const __attribute__((address_space(1))) void*)(Bw + (size_t)(bn + r) * K + k0 + sc * 8),
                (__attribute__((address_space(3))) void*)(Bs + ci * 8), 16, 0, 0);
        }
        __syncthreads();
#pragma unroll
        for (int kk = 0; kk < 2; ++kk) {
            bf16x8 af[4], bfr[4];
            const int kc = kk * 4 + (lane >> 4);
#pragma unroll
            for (int m = 0; m < 4; ++m) {
                int row = wr * 64 + m * 16 + (lane & 15);
                af[m] = *(const bf16x8*)&As[(row * 8 + (kc ^ (row & 7))) * 8];
            }
#pragma unroll
            for (int n = 0; n < 4; ++n) {
                int col = wc * 64 + n * 16 + (lane & 15);
                bfr[n] = *(const bf16x8*)&Bs[(col * 8 + (kc ^ (col & 7))) * 8];
            }
#pragma unroll
            for (int m = 0; m < 4; ++m)
#pragma unroll
                for (int n = 0; n < 4; ++n)
                    acc[m][n] = __builtin_amdgcn_mfma_f32_16x16x32_bf16(af[m], bfr[n], acc[m][n], 0, 0, 0);
        }
        __syncthreads();
    }
#pragma unroll
    for (int m = 0; m < 4; ++m) {
        int row0 = bm + wr * 64 + m * 16 + ((lane >> 4) << 2);
#pragma unroll
        for (int n = 0; n < 4; ++n) {
            int col = bn + wc * 64 + n * 16 + (lane & 15);
#pragma unroll
            for (int j = 0; j < 4; ++j) {
                size_t idx = (size_t)(row0 + j) * N + col;
                float v = acc[m][n][j];
                if (ADD_RES) v += Res[idx];
                C[idx] = v;
            }
        }
    }
}

// ---------------- qkv fp32 [2048][3072] -> Qh, Kh bf16 [32 bh][1024 t][64 dh] ----------------
__global__ void k_qk_split(const float* __restrict__ qkv,
                           unsigned short* __restrict__ Qh, unsigned short* __restrict__ Kh) {
    int row = blockIdx.x;                 // b*1024 + t
    int b = row >> 10, t = row & 1023;
    int tid = threadIdx.x;
    int hh = tid >> 4;                    // 0..15
    int dh = (tid & 15) * 4;
    const float* qr = qkv + (size_t)row * (3 * Dc);
#pragma unroll
    for (int p = 0; p < 2; ++p) {
        float4 v = *(const float4*)(qr + p * Dc + hh * 64 + dh);
        ushort4 o;
        o.x = f2b(v.x); o.y = f2b(v.y); o.z = f2b(v.z); o.w = f2b(v.w);
        unsigned short* dst = (p == 0) ? Qh : Kh;
        *(ushort4*)(dst + ((size_t)((b * Hc + hh) * Tc + t)) * 64 + dh) = o;
    }
}

// ---------------- V transpose: qkv fp32 -> Vt bf16 [32 bh][64 dh][1024 t] ----------------
__global__ void k_v_transpose(const float* __restrict__ qkv, unsigned short* __restrict__ Vt) {
    int t0 = blockIdx.x * 64;
    int bh = blockIdx.y;
    int b = bh >> 4, h = bh & 15;
    __shared__ unsigned short lds[64][65];
    int tid = threadIdx.x;
#pragma unroll
    for (int i = 0; i < 16; ++i) {
        int e = i * 256 + tid;
        int tl = e >> 6, dh = e & 63;
        lds[tl][dh] = f2b(qkv[(size_t)(b * Tc + t0 + tl) * (3 * Dc) + 2 * Dc + h * 64 + dh]);
    }
    __syncthreads();
#pragma unroll
    for (int i = 0; i < 16; ++i) {
        int e = i * 256 + tid;
        int dh = e >> 6, sl = e & 63;
        Vt[((size_t)(bh * 64 + dh)) * Tc + t0 + sl] = lds[sl][dh];
    }
}

// ---------------- MFMA attention: block = (b, h, 64 q-rows), 4 waves x 16 rows ----------------
// Two-pass (exact row max, then rational-softmax + PV). Qh/Kh [bh][t][64], Vt [bh][64][t].
__global__ __launch_bounds__(256) void k_attn_mfma(
    const unsigned short* __restrict__ Qh, const unsigned short* __restrict__ Kh,
    const unsigned short* __restrict__ Vt, unsigned short* __restrict__ o) {
    const int q0 = blockIdx.x * 64;
    const int h = blockIdx.y, b = blockIdx.z;
    const int bh = b * Hc + h;
    const float slope = exp2f(-0.5f * (float)(h + 1));

    __shared__ __align__(16) unsigned short Ks[64 * 64];
    __shared__ __align__(16) unsigned short Vs[64 * 64];
    __shared__ __align__(16) unsigned short Ps[4][16 * 64];

    const int tid = threadIdx.x, lane = tid & 63, wid = tid >> 6;
    const int q0w = q0 + wid * 16;
    const int l15 = lane & 15, g = lane >> 4;

    // Q fragments: row q0w + l15, dh = g*8 + kc*32
    const unsigned short* qbase = Qh + ((size_t)(bh * Tc + q0w + l15)) * 64 + g * 8;
    bf16x8 qf[2];
    qf[0] = *(const bf16x8*)qbase;
    qf[1] = *(const bf16x8*)(qbase + 32);

    const int nt = q0 / 64 + 1;

    // ---------- pass A: exact row max ----------
    f32x4 mx = {-3e38f, -3e38f, -3e38f, -3e38f};
    for (int it = 0; it < nt; ++it) {
        const int st = it * 64;
        __syncthreads();
#pragma unroll
        for (int half = 0; half < 2; ++half) {
            int ci = half * 256 + tid;
            int r = ci >> 3, sc = (ci & 7) ^ (r & 7);
            __builtin_amdgcn_global_load_lds(
                (const __attribute__((address_space(1))) void*)(Kh + ((size_t)(bh * Tc + st + r)) * 64 + sc * 8),
                (__attribute__((address_space(3))) void*)(Ks + ci * 8), 16, 0, 0);
        }
        __syncthreads();
#pragma unroll
        for (int si = 0; si < 4; ++si) {
            f32x4 d = {0.f, 0.f, 0.f, 0.f};
#pragma unroll
            for (int kc = 0; kc < 2; ++kc) {
                int r2 = si * 16 + l15;
                int c2 = kc * 4 + g;
                bf16x8 bk = *(const bf16x8*)&Ks[(r2 * 8 + (c2 ^ (r2 & 7))) * 8];
                d = __builtin_amdgcn_mfma_f32_16x16x32_bf16(qf[kc], bk, d, 0, 0, 0);
            }
            int s = st + si * 16 + l15;
#pragma unroll
            for (int j = 0; j < 4; ++j) {
                int t = q0w + g * 4 + j;
                float scv = (s <= t) ? d[j] * SCALEc - slope * (float)(t - s) : -3e38f;
                mx[j] = fmaxf(mx[j], scv);
            }
        }
    }
#pragma unroll
    for (int m = 8; m >= 1; m >>= 1)
#pragma unroll
        for (int j = 0; j < 4; ++j) mx[j] = fmaxf(mx[j], __shfl_xor(mx[j], m));

    // ---------- pass B: numerators, sum, PV ----------
    f32x4 sum = {0.f, 0.f, 0.f, 0.f};
    f32x4 oacc[4] = {};
    for (int it = 0; it < nt; ++it) {
        const int st = it * 64;
        __syncthreads();
#pragma unroll
        for (int half = 0; half < 2; ++half) {
            int ci = half * 256 + tid;
            int r = ci >> 3, sc = (ci & 7) ^ (r & 7);
            __builtin_amdgcn_global_load_lds(
                (const __attribute__((address_space(1))) void*)(Kh + ((size_t)(bh * Tc + st + r)) * 64 + sc * 8),
                (__attribute__((address_space(3))) void*)(Ks + ci * 8), 16, 0, 0);
            __builtin_amdgcn_global_load_lds(
                (const __attribute__((address_space(1))) void*)(Vt + ((size_t)(bh * 64 + r)) * Tc + st + sc * 8),
                (__attribute__((address_space(3))) void*)(Vs + ci * 8), 16, 0, 0);
        }
        __syncthreads();
#pragma unroll
        for (int si = 0; si < 4; ++si) {
            f32x4 d = {0.f, 0.f, 0.f, 0.f};
#pragma unroll
            for (int kc = 0; kc < 2; ++kc) {
                int r2 = si * 16 + l15;
                int c2 = kc * 4 + g;
                bf16x8 bk = *(const bf16x8*)&Ks[(r2 * 8 + (c2 ^ (r2 & 7))) * 8];
                d = __builtin_amdgcn_mfma_f32_16x16x32_bf16(qf[kc], bk, d, 0, 0, 0);
            }
            int sl = si * 16 + l15;          // local col in tile
            int s = st + sl;
            int chunk = sl >> 3, coff = sl & 7;
#pragma unroll
            for (int j = 0; j < 4; ++j) {
                int t = q0w + g * 4 + j;
                int q = g * 4 + j;
                unsigned short pb = 0;
                if (s <= t) {
                    float sv = d[j] * SCALEc - slope * (float)(t - s) - mx[j];
                    float num = __builtin_amdgcn_rcpf(fmaf(0.5f * sv, sv, 1.0f - sv));
                    sum[j] += num;
                    pb = f2b(num);
                }
                Ps[wid][q * 64 + ((chunk ^ (q & 7)) * 8) + coff] = pb;
            }
        }
        __syncthreads();   // P visibility (cross-lane)
#pragma unroll
        for (int kc = 0; kc < 2; ++kc) {
            int c2 = kc * 4 + g;
            bf16x8 pa = *(const bf16x8*)&Ps[wid][(l15 * 8 + (c2 ^ (l15 & 7))) * 8];
#pragma unroll
            for (int n = 0; n < 4; ++n) {
                int r2 = n * 16 + l15;
                bf16x8 vb = *(const bf16x8*)&Vs[(r2 * 8 + (c2 ^ (r2 & 7))) * 8];
                oacc[n] = __builtin_amdgcn_mfma_f32_16x16x32_bf16(pa, vb, oacc[n], 0, 0, 0);
            }
        }
    }
#pragma unroll
    for (int m = 8; m >= 1; m >>= 1)
#pragma unroll
        for (int j = 0; j < 4; ++j) sum[j] += __shfl_xor(sum[j], m);

    // epilogue: add analytic masked-denominator term, normalize, store
#pragma unroll
    for (int j = 0; j < 4; ++j) {
        int t = q0w + g * 4 + j;
        float svm = NEGc - mx[j];
        float mnum = __builtin_amdgcn_rcpf(fmaf(0.5f * svm, svm, 1.0f - svm));
        float inv = __builtin_amdgcn_rcpf(sum[j] + (float)(Tc - 1 - t) * mnum + EPSc);
#pragma unroll
        for (int n = 0; n < 4; ++n) {
            o[((size_t)(b * Tc + t)) * Dc + h * 64 + n * 16 + l15] = f2b(oacc[n][j] * inv);
        }
    }
}

// ---------------- gate elementwise ----------------
__global__ void k_gate(const float* __restrict__ gv, unsigned short* __restrict__ g) {
    int m = blockIdx.y;
    int f = blockIdx.x * 256 + threadIdx.x;
    if (f >= Fp) return;
    unsigned short out = 0;
    if (f < Fc) {
        float gate = gv[(size_t)m * Gp + f];
        float val = gv[(size_t)m * Gp + Fc + f];
        float sigma = 0.5f * (gate / (fabsf(gate) + 1.0f) + 1.0f);
        out = f2b(gate * sigma * val);
    }
    g[(size_t)m * Fp + f] = out;
}

extern "C" void kernel_launch(void* const* d_in, const int* in_sizes, int n_in,
                              void* d_out, int out_size, void* d_ws, size_t ws_size,
                              hipStream_t stream) {
    const int* ids = (const int*)d_in[0];
    const float* embed_w = (const float*)d_in[1];
    const float* qkv_w = (const float*)d_in[2];
    const float* out_w = (const float*)d_in[3];
    const float* gate_w = (const float*)d_in[4];
    const float* wout_w = (const float*)d_in[5];
    const float* n1 = (const float*)d_in[6];
    const float* n2 = (const float*)d_in[7];
    const float* nf = (const float*)d_in[8];
    float* outp = (float*)d_out;

    char* ws = (char*)d_ws;
    float* x = (float*)(ws + 0);                                   //  8,388,608
    unsigned short* h = (unsigned short*)(ws + 8388608);           //  4,194,304 (h / o share)
    float* qkv = (float*)(ws + 12582912);                          // 25,165,824 fp32 qkv
    float* gv = qkv;                                               // gv overlays (45,088,768 max)
    unsigned short* Qh = (unsigned short*)(ws + 37748736);         //  4,194,304
    unsigned short* Kh = (unsigned short*)(ws + 41943040);         //  4,194,304
    unsigned short* Vt = (unsigned short*)(ws + 46137344);         //  4,194,304 (end 50,331,648)
    unsigned short* g = (unsigned short*)(ws + 57671680);          // 11,272,192
    unsigned short* w1 = (unsigned short*)(ws + 68943872);         //  6,291,456 (wq / ww share)
    unsigned short* wo_b = (unsigned short*)(ws + 75235328);       //  2,097,152
    unsigned short* wg_b = (unsigned short*)(ws + 77332480);       // 11,272,192 (end 88,604,672)
    unsigned short* emb_b = (unsigned short*)(ws + 12582912);      // 65,536,000 (end-of-launch overlay)

    dim3 blk(256);

    k_embed<<<dim3(Mc), blk, 0, stream>>>(ids, embed_w, x);

    for (int l = 0; l < 4; l++) {
        const float* wq = qkv_w + (size_t)l * 3 * Dc * Dc;
        const float* wo = out_w + (size_t)l * Dc * Dc;
        const float* wg = gate_w + (size_t)l * 2 * Fc * Dc;
        const float* ww = wout_w + (size_t)l * Dc * Fc;

        k_conv<<<dim3(3072), blk, 0, stream>>>(wq, w1);
        k_conv<<<dim3(1024), blk, 0, stream>>>(wo, wo_b);
        k_conv_padrows<<<dim3(Gp), blk, 0, stream>>>(wg, wg_b, 2 * Fc);

        // h = me_norm(x, n1) -> bf16
        k_menorm_b<<<dim3(Mc), blk, 0, stream>>>(x, n1 + (size_t)l * Dc, h);
        // qkv = h @ wq^T   (N=3072, K=1024)
        k_mfma_gemm<false><<<dim3(24, 16), blk, 0, stream>>>(h, w1, nullptr, qkv, 3 * Dc, Dc);
        // split/convert to head-major bf16 + transposed V
        k_qk_split<<<dim3(Mc), blk, 0, stream>>>(qkv, Qh, Kh);
        k_v_transpose<<<dim3(Tc / 64, Bc * Hc), blk, 0, stream>>>(qkv, Vt);
        // ww -> w1 (wq no longer needed)
        k_conv_padk<<<dim3(1024), blk, 0, stream>>>(ww, w1);
        // attention -> o (bf16, into h buffer)
        k_attn_mfma<<<dim3(Tc / 64, Hc, Bc), blk, 0, stream>>>(Qh, Kh, Vt, h);
        // x = x + o @ wo^T  (N=1024, K=1024)
        k_mfma_gemm<true><<<dim3(8, 16), blk, 0, stream>>>(h, wo_b, x, x, Dc, Dc);
        // h = me_norm(x, n2)
        k_menorm_b<<<dim3(Mc), blk, 0, stream>>>(x, n2 + (size_t)l * Dc, h);
        // gv = h @ wg^T  (N=5504 padded, K=1024)
        k_mfma_gemm<false><<<dim3(Gp / 128, 16), blk, 0, stream>>>(h, wg_b, nullptr, gv, Gp, Dc);
        // g = gate*sigma*val -> bf16, K padded to 2752
        k_gate<<<dim3((Fp + 255) / 256, Mc), blk, 0, stream>>>(gv, g);
        // x = x + g @ ww^T  (N=1024, K=2752 padded)
        k_mfma_gemm<true><<<dim3(8, 16), blk, 0, stream>>>(g, w1, x, x, Dc, Fp);
    }

    // final norm + logits
    k_menorm_b<<<dim3(Mc), blk, 0, stream>>>(x, nf, h);
    k_conv<<<dim3(32000), blk, 0, stream>>>(embed_w, emb_b);
    // logits = h @ embed^T  (N=32000, K=1024)
    k_mfma_gemm<false><<<dim3(250, 16), blk, 0, stream>>>(h, emb_b, nullptr, outp, 32000, Dc);
}

// Round 5
// 1110.641 us; speedup vs baseline: 12.0745x; 1.1090x over previous
//
#include <hip/hip_runtime.h>
#include <math.h>

typedef __attribute__((ext_vector_type(8))) short bf16x8;
typedef __attribute__((ext_vector_type(4))) float f32x4;

namespace {
constexpr int Bc = 2, Tc = 1024, Dc = 1024, Hc = 16, Fc = 2730;
constexpr int Fp = 2752;   // padded F (K of wout GEMM)
constexpr int Gp = 5504;   // padded 2F (N of gate GEMM)
constexpr int Mc = Bc * Tc;               // 2048 rows
constexpr float EPSc = 1e-6f;
constexpr float NEGc = -10000.0f;
constexpr float SCALEc = 0.125f;          // 1/sqrt(64)
}

// fp32 -> bf16 RTNE (finite values only, which holds here)
__device__ __forceinline__ unsigned short f2b(float f) {
    unsigned int u = __float_as_uint(f);
    u += 0x7FFFu + ((u >> 16) & 1u);
    return (unsigned short)(u >> 16);
}

// ---------------- embedding gather (fp32 x) ----------------
__global__ void k_embed(const int* __restrict__ ids, const float* __restrict__ ew,
                        float* __restrict__ x) {
    int row = blockIdx.x;
    int id = ids[row];
    const float4* src = (const float4*)(ew + (size_t)id * Dc);
    float4* dst = (float4*)(x + (size_t)row * Dc);
    dst[threadIdx.x] = src[threadIdx.x];
}

// ---------------- straight fp32 -> bf16 convert, rows of 1024 ----------------
__global__ void k_conv(const float* __restrict__ in, unsigned short* __restrict__ out) {
    size_t i = ((size_t)blockIdx.x * 256 + threadIdx.x) * 4;
    float4 v = *(const float4*)(in + i);
    ushort4 o;
    o.x = f2b(v.x); o.y = f2b(v.y); o.z = f2b(v.z); o.w = f2b(v.w);
    *(ushort4*)(out + i) = o;
}

// ---------------- gate weight convert, INTERLEAVED: out row 2f = gate_f, 2f+1 = val_f ----------------
__global__ void k_conv_gate_ilv(const float* __restrict__ in, unsigned short* __restrict__ out) {
    int r = blockIdx.x;                   // 0..Gp-1
    int c = threadIdx.x * 4;
    ushort4 o;
    if (r < 2 * Fc) {
        int src = (r >> 1) + (r & 1) * Fc;
        float4 v = *(const float4*)(in + (size_t)src * Dc + c);
        o.x = f2b(v.x); o.y = f2b(v.y); o.z = f2b(v.z); o.w = f2b(v.w);
    } else {
        o.x = o.y = o.z = o.w = 0;
    }
    *(ushort4*)(out + (size_t)r * Dc + c) = o;
}

// ---------------- wout weight convert with col pad: [1024][Fc] -> [1024][Fp] ----------------
__global__ void k_conv_padk(const float* __restrict__ in, unsigned short* __restrict__ out) {
    int r = blockIdx.x;
    for (int c = threadIdx.x; c < Fp; c += 256) {
        float v = (c < Fc) ? in[(size_t)r * Fc + c] : 0.0f;
        out[(size_t)r * Fp + c] = f2b(v);
    }
}

// ---------------- me_norm -> bf16 out ----------------
__global__ void k_menorm_b(const float* __restrict__ x, const float* __restrict__ w,
                           unsigned short* __restrict__ out) {
    int row = blockIdx.x;
    float4 v = ((const float4*)(x + (size_t)row * Dc))[threadIdx.x];
    float s = fabsf(v.x) + fabsf(v.y) + fabsf(v.z) + fabsf(v.w);
#pragma unroll
    for (int m = 32; m >= 1; m >>= 1) s += __shfl_xor(s, m);
    __shared__ float ws4[4];
    if ((threadIdx.x & 63) == 0) ws4[threadIdx.x >> 6] = s;
    __syncthreads();
    float tot = ws4[0] + ws4[1] + ws4[2] + ws4[3];
    float inv = 1.0f / (tot / (float)Dc + EPSc);
    float4 wv = ((const float4*)w)[threadIdx.x];
    ushort4 o;
    o.x = f2b(v.x * inv * wv.x);
    o.y = f2b(v.y * inv * wv.y);
    o.z = f2b(v.z * inv * wv.z);
    o.w = f2b(v.w * inv * wv.w);
    ((ushort4*)(out + (size_t)row * Dc))[threadIdx.x] = o;
}

// ---------------- MFMA GEMM (m97 structure, grid-transposed: bm on blockIdx.x) ----------------
// MODE 0: C = A@B^T (fp32). MODE 1: C = Res + A@B^T. MODE 2: qkv fused epilogue ->
// U0=Qh,U1=Kh [bh][t][64] bf16, U2=Vt [bh][64][t] bf16. MODE 3: gate fused epilogue ->
// U0 = g [2048][Fp] bf16, g = gate*sigma*val from interleaved cols.
template <int MODE>
__global__ __launch_bounds__(256) void k_mfma_gemm(
    const unsigned short* __restrict__ A, const unsigned short* __restrict__ Bw,
    const float* __restrict__ Res, float* __restrict__ C,
    unsigned short* __restrict__ U0, unsigned short* __restrict__ U1,
    unsigned short* __restrict__ U2, int N, int K) {
    __shared__ __align__(16) unsigned short As[128 * 64];
    __shared__ __align__(16) unsigned short Bs[128 * 64];
    const int tid = threadIdx.x;
    const int lane = tid & 63;
    const int wid = tid >> 6;
    const int wr = wid >> 1, wc = wid & 1;
    const int bm = blockIdx.x * 128, bn = blockIdx.y * 128;
    const int l15 = lane & 15, g = lane >> 4;

    f32x4 acc[4][4] = {};

    const int nk = K >> 6;
    for (int kt = 0; kt < nk; ++kt) {
        const int k0 = kt << 6;
#pragma unroll
        for (int it = 0; it < 4; ++it) {
            int ci = it * 256 + tid;
            int r = ci >> 3;
            int sc = (ci & 7) ^ (r & 7);
            __builtin_amdgcn_global_load_lds(
                (const __attribute__((address_space(1))) void*)(A + (size_t)(bm + r) * K + k0 + sc * 8),
                (__attribute__((address_space(3))) void*)(As + ci * 8), 16, 0, 0);
            __builtin_amdgcn_global_load_lds(
                (const __attribute__((address_space(1))) void*)(Bw + (size_t)(bn + r) * K + k0 + sc * 8),
                (__attribute__((address_space(3))) void*)(Bs + ci * 8), 16, 0, 0);
        }
        __syncthreads();
#pragma unroll
        for (int kk = 0; kk < 2; ++kk) {
            bf16x8 af[4], bfr[4];
            const int kc = kk * 4 + g;
#pragma unroll
            for (int m = 0; m < 4; ++m) {
                int row = wr * 64 + m * 16 + l15;
                af[m] = *(const bf16x8*)&As[(row * 8 + (kc ^ (row & 7))) * 8];
            }
#pragma unroll
            for (int n = 0; n < 4; ++n) {
                int col = wc * 64 + n * 16 + l15;
                bfr[n] = *(const bf16x8*)&Bs[(col * 8 + (kc ^ (col & 7))) * 8];
            }
#pragma unroll
            for (int m = 0; m < 4; ++m)
#pragma unroll
                for (int n = 0; n < 4; ++n)
                    acc[m][n] = __builtin_amdgcn_mfma_f32_16x16x32_bf16(af[m], bfr[n], acc[m][n], 0, 0, 0);
        }
        __syncthreads();
    }

    // epilogue: C/D mapping col = lane&15, row = (lane>>4)*4 + j  [m89-verified]
#pragma unroll
    for (int m = 0; m < 4; ++m) {
        int row0 = bm + wr * 64 + m * 16 + (g << 2);
#pragma unroll
        for (int n = 0; n < 4; ++n) {
            int col = bn + wc * 64 + n * 16 + l15;
            if constexpr (MODE == 0 || MODE == 1) {
#pragma unroll
                for (int j = 0; j < 4; ++j) {
                    size_t idx = (size_t)(row0 + j) * N + col;
                    float v = acc[m][n][j];
                    if (MODE == 1) v += Res[idx];
                    C[idx] = v;
                }
            } else if constexpr (MODE == 2) {
                if (col < 2048) {
                    unsigned short* dst = (col < 1024) ? U0 : U1;
                    int hh = (col & 1023) >> 6, dh = col & 63;
#pragma unroll
                    for (int j = 0; j < 4; ++j) {
                        int row = row0 + j;
                        int b = row >> 10, t = row & 1023;
                        dst[((size_t)((b * Hc + hh) * Tc + t)) * 64 + dh] = f2b(acc[m][n][j]);
                    }
                } else {
                    int hh = (col >> 6) & 15, dh = col & 63;
                    int b = row0 >> 10, t = row0 & 1023;
                    ushort4 o4;
                    o4.x = f2b(acc[m][n][0]); o4.y = f2b(acc[m][n][1]);
                    o4.z = f2b(acc[m][n][2]); o4.w = f2b(acc[m][n][3]);
                    *(ushort4*)&U2[((size_t)((b * Hc + hh) * 64 + dh)) * Tc + t] = o4;
                }
            } else {  // MODE 3: gate
                float pv[4];
#pragma unroll
                for (int j = 0; j < 4; ++j) pv[j] = __shfl_xor(acc[m][n][j], 1);
                if ((l15 & 1) == 0) {
                    int f = col >> 1;
#pragma unroll
                    for (int j = 0; j < 4; ++j) {
                        float gate = acc[m][n][j], val = pv[j];
                        float sigma = 0.5f * (gate / (fabsf(gate) + 1.0f) + 1.0f);
                        U0[(size_t)(row0 + j) * Fp + f] = f2b(gate * sigma * val);
                    }
                }
            }
        }
    }
}

// ---------------- MFMA attention: block = (b, h, 64 q-rows), 4 waves x 16 rows ----------------
__global__ __launch_bounds__(256) void k_attn_mfma(
    const unsigned short* __restrict__ Qh, const unsigned short* __restrict__ Kh,
    const unsigned short* __restrict__ Vt, unsigned short* __restrict__ o) {
    const int q0 = blockIdx.x * 64;
    const int h = blockIdx.y, b = blockIdx.z;
    const int bh = b * Hc + h;
    const float slope = exp2f(-0.5f * (float)(h + 1));

    __shared__ __align__(16) unsigned short Ks[64 * 64];
    __shared__ __align__(16) unsigned short Vs[64 * 64];
    __shared__ __align__(16) unsigned short Ps[4][16 * 64];

    const int tid = threadIdx.x, lane = tid & 63, wid = tid >> 6;
    const int q0w = q0 + wid * 16;
    const int l15 = lane & 15, g = lane >> 4;

    const unsigned short* qbase = Qh + ((size_t)(bh * Tc + q0w + l15)) * 64 + g * 8;
    bf16x8 qf[2];
    qf[0] = *(const bf16x8*)qbase;
    qf[1] = *(const bf16x8*)(qbase + 32);

    const int nt = q0 / 64 + 1;

    // ---------- pass A: exact row max ----------
    f32x4 mx = {-3e38f, -3e38f, -3e38f, -3e38f};
    for (int it = 0; it < nt; ++it) {
        const int st = it * 64;
        __syncthreads();
#pragma unroll
        for (int half = 0; half < 2; ++half) {
            int ci = half * 256 + tid;
            int r = ci >> 3, sc = (ci & 7) ^ (r & 7);
            __builtin_amdgcn_global_load_lds(
                (const __attribute__((address_space(1))) void*)(Kh + ((size_t)(bh * Tc + st + r)) * 64 + sc * 8),
                (__attribute__((address_space(3))) void*)(Ks + ci * 8), 16, 0, 0);
        }
        __syncthreads();
#pragma unroll
        for (int si = 0; si < 4; ++si) {
            f32x4 d = {0.f, 0.f, 0.f, 0.f};
#pragma unroll
            for (int kc = 0; kc < 2; ++kc) {
                int r2 = si * 16 + l15;
                int c2 = kc * 4 + g;
                bf16x8 bk = *(const bf16x8*)&Ks[(r2 * 8 + (c2 ^ (r2 & 7))) * 8];
                d = __builtin_amdgcn_mfma_f32_16x16x32_bf16(qf[kc], bk, d, 0, 0, 0);
            }
            int s = st + si * 16 + l15;
#pragma unroll
            for (int j = 0; j < 4; ++j) {
                int t = q0w + g * 4 + j;
                float scv = (s <= t) ? d[j] * SCALEc - slope * (float)(t - s) : -3e38f;
                mx[j] = fmaxf(mx[j], scv);
            }
        }
    }
#pragma unroll
    for (int m = 8; m >= 1; m >>= 1)
#pragma unroll
        for (int j = 0; j < 4; ++j) mx[j] = fmaxf(mx[j], __shfl_xor(mx[j], m));

    // ---------- pass B: numerators, sum, PV ----------
    f32x4 sum = {0.f, 0.f, 0.f, 0.f};
    f32x4 oacc[4] = {};
    for (int it = 0; it < nt; ++it) {
        const int st = it * 64;
        __syncthreads();
#pragma unroll
        for (int half = 0; half < 2; ++half) {
            int ci = half * 256 + tid;
            int r = ci >> 3, sc = (ci & 7) ^ (r & 7);
            __builtin_amdgcn_global_load_lds(
                (const __attribute__((address_space(1))) void*)(Kh + ((size_t)(bh * Tc + st + r)) * 64 + sc * 8),
                (__attribute__((address_space(3))) void*)(Ks + ci * 8), 16, 0, 0);
            __builtin_amdgcn_global_load_lds(
                (const __attribute__((address_space(1))) void*)(Vt + ((size_t)(bh * 64 + r)) * Tc + st + sc * 8),
                (__attribute__((address_space(3))) void*)(Vs + ci * 8), 16, 0, 0);
        }
        __syncthreads();
#pragma unroll
        for (int si = 0; si < 4; ++si) {
            f32x4 d = {0.f, 0.f, 0.f, 0.f};
#pragma unroll
            for (int kc = 0; kc < 2; ++kc) {
                int r2 = si * 16 + l15;
                int c2 = kc * 4 + g;
                bf16x8 bk = *(const bf16x8*)&Ks[(r2 * 8 + (c2 ^ (r2 & 7))) * 8];
                d = __builtin_amdgcn_mfma_f32_16x16x32_bf16(qf[kc], bk, d, 0, 0, 0);
            }
            int sl = si * 16 + l15;
            int s = st + sl;
            int chunk = sl >> 3, coff = sl & 7;
#pragma unroll
            for (int j = 0; j < 4; ++j) {
                int t = q0w + g * 4 + j;
                int q = g * 4 + j;
                unsigned short pb = 0;
                if (s <= t) {
                    float sv = d[j] * SCALEc - slope * (float)(t - s) - mx[j];
                    float num = __builtin_amdgcn_rcpf(fmaf(0.5f * sv, sv, 1.0f - sv));
                    sum[j] += num;
                    pb = f2b(num);
                }
                Ps[wid][q * 64 + ((chunk ^ (q & 7)) * 8) + coff] = pb;
            }
        }
        __syncthreads();
#pragma unroll
        for (int kc = 0; kc < 2; ++kc) {
            int c2 = kc * 4 + g;
            bf16x8 pa = *(const bf16x8*)&Ps[wid][(l15 * 8 + (c2 ^ (l15 & 7))) * 8];
#pragma unroll
            for (int n = 0; n < 4; ++n) {
                int r2 = n * 16 + l15;
                bf16x8 vb = *(const bf16x8*)&Vs[(r2 * 8 + (c2 ^ (r2 & 7))) * 8];
                oacc[n] = __builtin_amdgcn_mfma_f32_16x16x32_bf16(pa, vb, oacc[n], 0, 0, 0);
            }
        }
    }
#pragma unroll
    for (int m = 8; m >= 1; m >>= 1)
#pragma unroll
        for (int j = 0; j < 4; ++j) sum[j] += __shfl_xor(sum[j], m);

#pragma unroll
    for (int j = 0; j < 4; ++j) {
        int t = q0w + g * 4 + j;
        float svm = NEGc - mx[j];
        float mnum = __builtin_amdgcn_rcpf(fmaf(0.5f * svm, svm, 1.0f - svm));
        float inv = __builtin_amdgcn_rcpf(sum[j] + (float)(Tc - 1 - t) * mnum + EPSc);
#pragma unroll
        for (int n = 0; n < 4; ++n) {
            o[((size_t)(b * Tc + t)) * Dc + h * 64 + n * 16 + l15] = f2b(oacc[n][j] * inv);
        }
    }
}

extern "C" void kernel_launch(void* const* d_in, const int* in_sizes, int n_in,
                              void* d_out, int out_size, void* d_ws, size_t ws_size,
                              hipStream_t stream) {
    const int* ids = (const int*)d_in[0];
    const float* embed_w = (const float*)d_in[1];
    const float* qkv_w = (const float*)d_in[2];
    const float* out_w = (const float*)d_in[3];
    const float* gate_w = (const float*)d_in[4];
    const float* wout_w = (const float*)d_in[5];
    const float* n1 = (const float*)d_in[6];
    const float* n2 = (const float*)d_in[7];
    const float* nf = (const float*)d_in[8];
    float* outp = (float*)d_out;

    char* ws = (char*)d_ws;
    float* x = (float*)(ws + 0);                                   //  8,388,608
    unsigned short* h = (unsigned short*)(ws + 8388608);           //  4,194,304 (h / o share)
    unsigned short* Qh = (unsigned short*)(ws + 12582912);         //  4,194,304
    unsigned short* Kh = (unsigned short*)(ws + 16777216);         //  4,194,304
    unsigned short* Vt = (unsigned short*)(ws + 20971520);         //  4,194,304
    unsigned short* g = (unsigned short*)(ws + 25165824);          // 11,272,192
    unsigned short* w1 = (unsigned short*)(ws + 36438016);         //  6,291,456 (wq / ww share)
    unsigned short* wo_b = (unsigned short*)(ws + 42729472);       //  2,097,152
    unsigned short* wg_b = (unsigned short*)(ws + 44826624);       // 11,272,192 (end 56,098,816)
    unsigned short* emb_b = (unsigned short*)(ws + 12582912);      // 65,536,000 overlay (end 78,118,912)

    dim3 blk(256);

    k_embed<<<dim3(Mc), blk, 0, stream>>>(ids, embed_w, x);

    for (int l = 0; l < 4; l++) {
        const float* wq = qkv_w + (size_t)l * 3 * Dc * Dc;
        const float* wo = out_w + (size_t)l * Dc * Dc;
        const float* wg = gate_w + (size_t)l * 2 * Fc * Dc;
        const float* ww = wout_w + (size_t)l * Dc * Fc;

        k_conv<<<dim3(3072), blk, 0, stream>>>(wq, w1);
        k_conv<<<dim3(1024), blk, 0, stream>>>(wo, wo_b);
        k_conv_gate_ilv<<<dim3(Gp), blk, 0, stream>>>(wg, wg_b);

        // h = me_norm(x, n1) -> bf16
        k_menorm_b<<<dim3(Mc), blk, 0, stream>>>(x, n1 + (size_t)l * Dc, h);
        // qkv GEMM fused: writes Qh, Kh, Vt directly (N=3072, K=1024)
        k_mfma_gemm<2><<<dim3(16, 24), blk, 0, stream>>>(h, w1, nullptr, nullptr, Qh, Kh, Vt, 3 * Dc, Dc);
        // ww -> w1 (wq no longer needed)
        k_conv_padk<<<dim3(1024), blk, 0, stream>>>(ww, w1);
        // attention -> o (bf16, into h buffer)
        k_attn_mfma<<<dim3(Tc / 64, Hc, Bc), blk, 0, stream>>>(Qh, Kh, Vt, h);
        // x = x + o @ wo^T  (N=1024, K=1024)
        k_mfma_gemm<1><<<dim3(16, 8), blk, 0, stream>>>(h, wo_b, x, x, nullptr, nullptr, nullptr, Dc, Dc);
        // h = me_norm(x, n2)
        k_menorm_b<<<dim3(Mc), blk, 0, stream>>>(x, n2 + (size_t)l * Dc, h);
        // gate GEMM fused: g = gate*sigma*val bf16 (N=5504 interleaved, K=1024)
        k_mfma_gemm<3><<<dim3(16, Gp / 128), blk, 0, stream>>>(h, wg_b, nullptr, nullptr, g, nullptr, nullptr, Gp, Dc);
        // x = x + g @ ww^T  (N=1024, K=2752 padded)
        k_mfma_gemm<1><<<dim3(16, 8), blk, 0, stream>>>(g, w1, x, x, nullptr, nullptr, nullptr, Dc, Fp);
    }

    // final norm + logits
    k_menorm_b<<<dim3(Mc), blk, 0, stream>>>(x, nf, h);
    k_conv<<<dim3(32000), blk, 0, stream>>>(embed_w, emb_b);
    // logits = h @ embed^T  (N=32000, K=1024)
    k_mfma_gemm<0><<<dim3(16, 250), blk, 0, stream>>>(h, emb_b, nullptr, outp, nullptr, nullptr, nullptr, 32000, Dc);
}

// Round 6
// 1052.526 us; speedup vs baseline: 12.7412x; 1.0552x over previous
//
#include <hip/hip_runtime.h>
#include <math.h>

typedef __attribute__((ext_vector_type(8))) short bf16x8;
typedef __attribute__((ext_vector_type(4))) float f32x4;

namespace {
constexpr int Bc = 2, Tc = 1024, Dc = 1024, Hc = 16, Fc = 2730;
constexpr int Fp = 2752;   // padded F (K of wout GEMM)
constexpr int Gp = 5504;   // padded 2F (N of gate GEMM)
constexpr int Mc = Bc * Tc;               // 2048 rows
constexpr float EPSc = 1e-6f;
constexpr float NEGc = -10000.0f;
constexpr float SCALEc = 0.125f;          // 1/sqrt(64)
}

// fp32 -> bf16 RTNE (finite values only, which holds here)
__device__ __forceinline__ unsigned short f2b(float f) {
    unsigned int u = __float_as_uint(f);
    u += 0x7FFFu + ((u >> 16) & 1u);
    return (unsigned short)(u >> 16);
}

// ---------------- embedding gather (fp32 x) ----------------
__global__ void k_embed(const int* __restrict__ ids, const float* __restrict__ ew,
                        float* __restrict__ x) {
    int row = blockIdx.x;
    int id = ids[row];
    const float4* src = (const float4*)(ew + (size_t)id * Dc);
    float4* dst = (float4*)(x + (size_t)row * Dc);
    dst[threadIdx.x] = src[threadIdx.x];
}

// ---------------- straight fp32 -> bf16 convert, rows of 1024 ----------------
__global__ void k_conv(const float* __restrict__ in, unsigned short* __restrict__ out) {
    size_t i = ((size_t)blockIdx.x * 256 + threadIdx.x) * 4;
    float4 v = *(const float4*)(in + i);
    ushort4 o;
    o.x = f2b(v.x); o.y = f2b(v.y); o.z = f2b(v.z); o.w = f2b(v.w);
    *(ushort4*)(out + i) = o;
}

// ---------------- gate weight convert, INTERLEAVED: out row 2f = gate_f, 2f+1 = val_f ----------------
__global__ void k_conv_gate_ilv(const float* __restrict__ in, unsigned short* __restrict__ out) {
    int r = blockIdx.x;                   // 0..Gp-1
    int c = threadIdx.x * 4;
    ushort4 o;
    if (r < 2 * Fc) {
        int src = (r >> 1) + (r & 1) * Fc;
        float4 v = *(const float4*)(in + (size_t)src * Dc + c);
        o.x = f2b(v.x); o.y = f2b(v.y); o.z = f2b(v.z); o.w = f2b(v.w);
    } else {
        o.x = o.y = o.z = o.w = 0;
    }
    *(ushort4*)(out + (size_t)r * Dc + c) = o;
}

// ---------------- wout weight convert with col pad: [1024][Fc] -> [1024][Fp] ----------------
__global__ void k_conv_padk(const float* __restrict__ in, unsigned short* __restrict__ out) {
    int r = blockIdx.x;
    for (int c = threadIdx.x; c < Fp; c += 256) {
        float v = (c < Fc) ? in[(size_t)r * Fc + c] : 0.0f;
        out[(size_t)r * Fp + c] = f2b(v);
    }
}

// ---------------- me_norm -> bf16 out ----------------
__global__ void k_menorm_b(const float* __restrict__ x, const float* __restrict__ w,
                           unsigned short* __restrict__ out) {
    int row = blockIdx.x;
    float4 v = ((const float4*)(x + (size_t)row * Dc))[threadIdx.x];
    float s = fabsf(v.x) + fabsf(v.y) + fabsf(v.z) + fabsf(v.w);
#pragma unroll
    for (int m = 32; m >= 1; m >>= 1) s += __shfl_xor(s, m);
    __shared__ float ws4[4];
    if ((threadIdx.x & 63) == 0) ws4[threadIdx.x >> 6] = s;
    __syncthreads();
    float tot = ws4[0] + ws4[1] + ws4[2] + ws4[3];
    float inv = 1.0f / (tot / (float)Dc + EPSc);
    float4 wv = ((const float4*)w)[threadIdx.x];
    ushort4 o;
    o.x = f2b(v.x * inv * wv.x);
    o.y = f2b(v.y * inv * wv.y);
    o.z = f2b(v.z * inv * wv.z);
    o.w = f2b(v.w * inv * wv.w);
    ((ushort4*)(out + (size_t)row * Dc))[threadIdx.x] = o;
}

// ---------------- MFMA GEMM (m97 structure + XCD swizzle; BM = 64 or 128) ----------------
// Grid: (M/BM, N/128), bm from swizzled x. MODE 0: C = A@B^T (fp32). MODE 1: += Res.
// MODE 2: qkv fused epilogue -> U0=Qh,U1=Kh [bh][t][64], U2=Vt [bh][64][t] (bf16).
// MODE 3: gate fused epilogue -> U0 = g [2048][Fp] bf16 from interleaved cols.
template <int MODE, int BM>
__global__ __launch_bounds__(256) void k_mfma_gemm(
    const unsigned short* __restrict__ A, const unsigned short* __restrict__ Bw,
    const float* __restrict__ Res, float* __restrict__ C,
    unsigned short* __restrict__ U0, unsigned short* __restrict__ U1,
    unsigned short* __restrict__ U2, int N, int K) {
    constexpr int MFR = BM / 32;          // A-frags / acc rows per wave
    __shared__ __align__(16) unsigned short As[BM * 64];
    __shared__ __align__(16) unsigned short Bs[128 * 64];
    const int tid = threadIdx.x;
    const int lane = tid & 63;
    const int wid = tid >> 6;
    const int wr = wid >> 1, wc = wid & 1;
    const int l15 = lane & 15, g = lane >> 4;

    // XCD-aware swizzle (T1): all M-tiles of one B-panel -> same XCD. nwg % 8 == 0 here.
    const int nwg = gridDim.x * gridDim.y;
    int w = blockIdx.y * gridDim.x + blockIdx.x;
    int f = (nwg & 7) ? w : ((w & 7) * (nwg >> 3) + (w >> 3));
    const int bm = (f % gridDim.x) * BM, bn = (f / gridDim.x) * 128;

    f32x4 acc[MFR][4] = {};

    const int nk = K >> 6;
    for (int kt = 0; kt < nk; ++kt) {
        const int k0 = kt << 6;
#pragma unroll
        for (int it = 0; it < MFR; ++it) {
            int ci = it * 256 + tid;
            int r = ci >> 3;
            int sc = (ci & 7) ^ (r & 7);
            __builtin_amdgcn_global_load_lds(
                (const __attribute__((address_space(1))) void*)(A + (size_t)(bm + r) * K + k0 + sc * 8),
                (__attribute__((address_space(3))) void*)(As + ci * 8), 16, 0, 0);
        }
#pragma unroll
        for (int it = 0; it < 4; ++it) {
            int ci = it * 256 + tid;
            int r = ci >> 3;
            int sc = (ci & 7) ^ (r & 7);
            __builtin_amdgcn_global_load_lds(
                (const __attribute__((address_space(1))) void*)(Bw + (size_t)(bn + r) * K + k0 + sc * 8),
                (__attribute__((address_space(3))) void*)(Bs + ci * 8), 16, 0, 0);
        }
        __syncthreads();
#pragma unroll
        for (int kk = 0; kk < 2; ++kk) {
            bf16x8 af[MFR], bfr[4];
            const int kc = kk * 4 + g;
#pragma unroll
            for (int m = 0; m < MFR; ++m) {
                int row = wr * (BM / 2) + m * 16 + l15;
                af[m] = *(const bf16x8*)&As[(row * 8 + (kc ^ (row & 7))) * 8];
            }
#pragma unroll
            for (int n = 0; n < 4; ++n) {
                int col = wc * 64 + n * 16 + l15;
                bfr[n] = *(const bf16x8*)&Bs[(col * 8 + (kc ^ (col & 7))) * 8];
            }
#pragma unroll
            for (int m = 0; m < MFR; ++m)
#pragma unroll
                for (int n = 0; n < 4; ++n)
                    acc[m][n] = __builtin_amdgcn_mfma_f32_16x16x32_bf16(af[m], bfr[n], acc[m][n], 0, 0, 0);
        }
        __syncthreads();
    }

    // epilogue: C/D mapping col = lane&15, row = (lane>>4)*4 + j  [m89-verified]
#pragma unroll
    for (int m = 0; m < MFR; ++m) {
        int row0 = bm + wr * (BM / 2) + m * 16 + (g << 2);
#pragma unroll
        for (int n = 0; n < 4; ++n) {
            int col = bn + wc * 64 + n * 16 + l15;
            if constexpr (MODE == 0 || MODE == 1) {
#pragma unroll
                for (int j = 0; j < 4; ++j) {
                    size_t idx = (size_t)(row0 + j) * N + col;
                    float v = acc[m][n][j];
                    if (MODE == 1) v += Res[idx];
                    C[idx] = v;
                }
            } else if constexpr (MODE == 2) {
                if (col < 2048) {
                    unsigned short* dst = (col < 1024) ? U0 : U1;
                    int hh = (col & 1023) >> 6, dh = col & 63;
#pragma unroll
                    for (int j = 0; j < 4; ++j) {
                        int row = row0 + j;
                        int b = row >> 10, t = row & 1023;
                        dst[((size_t)((b * Hc + hh) * Tc + t)) * 64 + dh] = f2b(acc[m][n][j]);
                    }
                } else {
                    int hh = (col >> 6) & 15, dh = col & 63;
                    int b = row0 >> 10, t = row0 & 1023;
                    ushort4 o4;
                    o4.x = f2b(acc[m][n][0]); o4.y = f2b(acc[m][n][1]);
                    o4.z = f2b(acc[m][n][2]); o4.w = f2b(acc[m][n][3]);
                    *(ushort4*)&U2[((size_t)((b * Hc + hh) * 64 + dh)) * Tc + t] = o4;
                }
            } else {  // MODE 3: gate
                float pv[4];
#pragma unroll
                for (int j = 0; j < 4; ++j) pv[j] = __shfl_xor(acc[m][n][j], 1);
                if ((l15 & 1) == 0) {
                    int fq = col >> 1;
#pragma unroll
                    for (int j = 0; j < 4; ++j) {
                        float gate = acc[m][n][j], val = pv[j];
                        float sigma = 0.5f * (gate / (fabsf(gate) + 1.0f) + 1.0f);
                        U0[(size_t)(row0 + j) * Fp + fq] = f2b(gate * sigma * val);
                    }
                }
            }
        }
    }
}

// ---------------- MFMA attention: block = (b, h, 64 q-rows), 4 waves x 16 rows ----------------
__global__ __launch_bounds__(256) void k_attn_mfma(
    const unsigned short* __restrict__ Qh, const unsigned short* __restrict__ Kh,
    const unsigned short* __restrict__ Vt, unsigned short* __restrict__ o) {
    const int q0 = blockIdx.x * 64;
    const int h = blockIdx.y, b = blockIdx.z;
    const int bh = b * Hc + h;
    const float slope = exp2f(-0.5f * (float)(h + 1));

    __shared__ __align__(16) unsigned short Ks[64 * 64];
    __shared__ __align__(16) unsigned short Vs[64 * 64];
    __shared__ __align__(16) unsigned short Ps[4][16 * 64];

    const int tid = threadIdx.x, lane = tid & 63, wid = tid >> 6;
    const int q0w = q0 + wid * 16;
    const int l15 = lane & 15, g = lane >> 4;

    const unsigned short* qbase = Qh + ((size_t)(bh * Tc + q0w + l15)) * 64 + g * 8;
    bf16x8 qf[2];
    qf[0] = *(const bf16x8*)qbase;
    qf[1] = *(const bf16x8*)(qbase + 32);

    const int nt = q0 / 64 + 1;

    // ---------- pass A: exact row max ----------
    f32x4 mx = {-3e38f, -3e38f, -3e38f, -3e38f};
    for (int it = 0; it < nt; ++it) {
        const int st = it * 64;
        __syncthreads();
#pragma unroll
        for (int half = 0; half < 2; ++half) {
            int ci = half * 256 + tid;
            int r = ci >> 3, sc = (ci & 7) ^ (r & 7);
            __builtin_amdgcn_global_load_lds(
                (const __attribute__((address_space(1))) void*)(Kh + ((size_t)(bh * Tc + st + r)) * 64 + sc * 8),
                (__attribute__((address_space(3))) void*)(Ks + ci * 8), 16, 0, 0);
        }
        __syncthreads();
#pragma unroll
        for (int si = 0; si < 4; ++si) {
            f32x4 d = {0.f, 0.f, 0.f, 0.f};
#pragma unroll
            for (int kc = 0; kc < 2; ++kc) {
                int r2 = si * 16 + l15;
                int c2 = kc * 4 + g;
                bf16x8 bk = *(const bf16x8*)&Ks[(r2 * 8 + (c2 ^ (r2 & 7))) * 8];
                d = __builtin_amdgcn_mfma_f32_16x16x32_bf16(qf[kc], bk, d, 0, 0, 0);
            }
            int s = st + si * 16 + l15;
#pragma unroll
            for (int j = 0; j < 4; ++j) {
                int t = q0w + g * 4 + j;
                float scv = (s <= t) ? d[j] * SCALEc - slope * (float)(t - s) : -3e38f;
                mx[j] = fmaxf(mx[j], scv);
            }
        }
    }
#pragma unroll
    for (int m = 8; m >= 1; m >>= 1)
#pragma unroll
        for (int j = 0; j < 4; ++j) mx[j] = fmaxf(mx[j], __shfl_xor(mx[j], m));

    // ---------- pass B: numerators, sum, PV ----------
    f32x4 sum = {0.f, 0.f, 0.f, 0.f};
    f32x4 oacc[4] = {};
    for (int it = 0; it < nt; ++it) {
        const int st = it * 64;
        __syncthreads();
#pragma unroll
        for (int half = 0; half < 2; ++half) {
            int ci = half * 256 + tid;
            int r = ci >> 3, sc = (ci & 7) ^ (r & 7);
            __builtin_amdgcn_global_load_lds(
                (const __attribute__((address_space(1))) void*)(Kh + ((size_t)(bh * Tc + st + r)) * 64 + sc * 8),
                (__attribute__((address_space(3))) void*)(Ks + ci * 8), 16, 0, 0);
            __builtin_amdgcn_global_load_lds(
                (const __attribute__((address_space(1))) void*)(Vt + ((size_t)(bh * 64 + r)) * Tc + st + sc * 8),
                (__attribute__((address_space(3))) void*)(Vs + ci * 8), 16, 0, 0);
        }
        __syncthreads();
#pragma unroll
        for (int si = 0; si < 4; ++si) {
            f32x4 d = {0.f, 0.f, 0.f, 0.f};
#pragma unroll
            for (int kc = 0; kc < 2; ++kc) {
                int r2 = si * 16 + l15;
                int c2 = kc * 4 + g;
                bf16x8 bk = *(const bf16x8*)&Ks[(r2 * 8 + (c2 ^ (r2 & 7))) * 8];
                d = __builtin_amdgcn_mfma_f32_16x16x32_bf16(qf[kc], bk, d, 0, 0, 0);
            }
            int sl = si * 16 + l15;
            int s = st + sl;
            int chunk = sl >> 3, coff = sl & 7;
#pragma unroll
            for (int j = 0; j < 4; ++j) {
                int t = q0w + g * 4 + j;
                int q = g * 4 + j;
                unsigned short pb = 0;
                if (s <= t) {
                    float sv = d[j] * SCALEc - slope * (float)(t - s) - mx[j];
                    float num = __builtin_amdgcn_rcpf(fmaf(0.5f * sv, sv, 1.0f - sv));
                    sum[j] += num;
                    pb = f2b(num);
                }
                Ps[wid][q * 64 + ((chunk ^ (q & 7)) * 8) + coff] = pb;
            }
        }
        __syncthreads();
#pragma unroll
        for (int kc = 0; kc < 2; ++kc) {
            int c2 = kc * 4 + g;
            bf16x8 pa = *(const bf16x8*)&Ps[wid][(l15 * 8 + (c2 ^ (l15 & 7))) * 8];
#pragma unroll
            for (int n = 0; n < 4; ++n) {
                int r2 = n * 16 + l15;
                bf16x8 vb = *(const bf16x8*)&Vs[(r2 * 8 + (c2 ^ (r2 & 7))) * 8];
                oacc[n] = __builtin_amdgcn_mfma_f32_16x16x32_bf16(pa, vb, oacc[n], 0, 0, 0);
            }
        }
    }
#pragma unroll
    for (int m = 8; m >= 1; m >>= 1)
#pragma unroll
        for (int j = 0; j < 4; ++j) sum[j] += __shfl_xor(sum[j], m);

#pragma unroll
    for (int j = 0; j < 4; ++j) {
        int t = q0w + g * 4 + j;
        float svm = NEGc - mx[j];
        float mnum = __builtin_amdgcn_rcpf(fmaf(0.5f * svm, svm, 1.0f - svm));
        float inv = __builtin_amdgcn_rcpf(sum[j] + (float)(Tc - 1 - t) * mnum + EPSc);
#pragma unroll
        for (int n = 0; n < 4; ++n) {
            o[((size_t)(b * Tc + t)) * Dc + h * 64 + n * 16 + l15] = f2b(oacc[n][j] * inv);
        }
    }
}

extern "C" void kernel_launch(void* const* d_in, const int* in_sizes, int n_in,
                              void* d_out, int out_size, void* d_ws, size_t ws_size,
                              hipStream_t stream) {
    const int* ids = (const int*)d_in[0];
    const float* embed_w = (const float*)d_in[1];
    const float* qkv_w = (const float*)d_in[2];
    const float* out_w = (const float*)d_in[3];
    const float* gate_w = (const float*)d_in[4];
    const float* wout_w = (const float*)d_in[5];
    const float* n1 = (const float*)d_in[6];
    const float* n2 = (const float*)d_in[7];
    const float* nf = (const float*)d_in[8];
    float* outp = (float*)d_out;

    char* ws = (char*)d_ws;
    float* x = (float*)(ws + 0);                                   //  8,388,608
    unsigned short* h = (unsigned short*)(ws + 8388608);           //  4,194,304 (h / o share)
    unsigned short* Qh = (unsigned short*)(ws + 12582912);         //  4,194,304
    unsigned short* Kh = (unsigned short*)(ws + 16777216);         //  4,194,304
    unsigned short* Vt = (unsigned short*)(ws + 20971520);         //  4,194,304
    unsigned short* g = (unsigned short*)(ws + 25165824);          // 11,272,192
    unsigned short* w1 = (unsigned short*)(ws + 36438016);         //  6,291,456 (wq / ww share)
    unsigned short* wo_b = (unsigned short*)(ws + 42729472);       //  2,097,152
    unsigned short* wg_b = (unsigned short*)(ws + 44826624);       // 11,272,192 (end 56,098,816)
    unsigned short* emb_b = (unsigned short*)(ws + 12582912);      // 65,536,000 overlay (end 78,118,912)

    dim3 blk(256);

    k_embed<<<dim3(Mc), blk, 0, stream>>>(ids, embed_w, x);

    for (int l = 0; l < 4; l++) {
        const float* wq = qkv_w + (size_t)l * 3 * Dc * Dc;
        const float* wo = out_w + (size_t)l * Dc * Dc;
        const float* wg = gate_w + (size_t)l * 2 * Fc * Dc;
        const float* ww = wout_w + (size_t)l * Dc * Fc;

        k_conv<<<dim3(3072), blk, 0, stream>>>(wq, w1);
        k_conv<<<dim3(1024), blk, 0, stream>>>(wo, wo_b);
        k_conv_gate_ilv<<<dim3(Gp), blk, 0, stream>>>(wg, wg_b);

        // h = me_norm(x, n1) -> bf16
        k_menorm_b<<<dim3(Mc), blk, 0, stream>>>(x, n1 + (size_t)l * Dc, h);
        // qkv GEMM fused: writes Qh, Kh, Vt directly (N=3072, K=1024)
        k_mfma_gemm<2, 128><<<dim3(16, 24), blk, 0, stream>>>(h, w1, nullptr, nullptr, Qh, Kh, Vt, 3 * Dc, Dc);
        // ww -> w1 (wq no longer needed)
        k_conv_padk<<<dim3(1024), blk, 0, stream>>>(ww, w1);
        // attention -> o (bf16, into h buffer)
        k_attn_mfma<<<dim3(Tc / 64, Hc, Bc), blk, 0, stream>>>(Qh, Kh, Vt, h);
        // x = x + o @ wo^T  (N=1024, K=1024), BM=64 -> 256 wgs
        k_mfma_gemm<1, 64><<<dim3(32, 8), blk, 0, stream>>>(h, wo_b, x, x, nullptr, nullptr, nullptr, Dc, Dc);
        // h = me_norm(x, n2)
        k_menorm_b<<<dim3(Mc), blk, 0, stream>>>(x, n2 + (size_t)l * Dc, h);
        // gate GEMM fused: g = gate*sigma*val bf16 (N=5504 interleaved, K=1024)
        k_mfma_gemm<3, 128><<<dim3(16, Gp / 128), blk, 0, stream>>>(h, wg_b, nullptr, nullptr, g, nullptr, nullptr, Gp, Dc);
        // x = x + g @ ww^T  (N=1024, K=2752 padded), BM=64 -> 256 wgs
        k_mfma_gemm<1, 64><<<dim3(32, 8), blk, 0, stream>>>(g, w1, x, x, nullptr, nullptr, nullptr, Dc, Fp);
    }

    // final norm + logits
    k_menorm_b<<<dim3(Mc), blk, 0, stream>>>(x, nf, h);
    k_conv<<<dim3(32000), blk, 0, stream>>>(embed_w, emb_b);
    // logits = h @ embed^T  (N=32000, K=1024)
    k_mfma_gemm<0, 128><<<dim3(16, 250), blk, 0, stream>>>(h, emb_b, nullptr, outp, nullptr, nullptr, nullptr, 32000, Dc);
}

// Round 7
// 1026.774 us; speedup vs baseline: 13.0608x; 1.0251x over previous
//
#include <hip/hip_runtime.h>
#include <math.h>

typedef __attribute__((ext_vector_type(8))) short bf16x8;
typedef __attribute__((ext_vector_type(4))) float f32x4;

namespace {
constexpr int Bc = 2, Tc = 1024, Dc = 1024, Hc = 16, Fc = 2730;
constexpr int Fp = 2752;   // padded F (K of wout GEMM)
constexpr int Gp = 5504;   // padded 2F (N of gate GEMM)
constexpr int Mc = Bc * Tc;               // 2048 rows
constexpr float EPSc = 1e-6f;
constexpr float NEGc = -10000.0f;
constexpr float SCALEc = 0.125f;          // 1/sqrt(64)
}

// fp32 -> bf16 RTNE (finite values only, which holds here)
__device__ __forceinline__ unsigned short f2b(float f) {
    unsigned int u = __float_as_uint(f);
    u += 0x7FFFu + ((u >> 16) & 1u);
    return (unsigned short)(u >> 16);
}

// ---------------- embedding gather (fp32 x) ----------------
__global__ void k_embed(const int* __restrict__ ids, const float* __restrict__ ew,
                        float* __restrict__ x) {
    int row = blockIdx.x;
    int id = ids[row];
    const float4* src = (const float4*)(ew + (size_t)id * Dc);
    float4* dst = (float4*)(x + (size_t)row * Dc);
    dst[threadIdx.x] = src[threadIdx.x];
}

// ---------------- straight fp32 -> bf16 convert, rows of 1024 ----------------
__global__ void k_conv(const float* __restrict__ in, unsigned short* __restrict__ out) {
    size_t i = ((size_t)blockIdx.x * 256 + threadIdx.x) * 4;
    float4 v = *(const float4*)(in + i);
    ushort4 o;
    o.x = f2b(v.x); o.y = f2b(v.y); o.z = f2b(v.z); o.w = f2b(v.w);
    *(ushort4*)(out + i) = o;
}

// ---------------- gate weight convert, INTERLEAVED: out row 2f = gate_f, 2f+1 = val_f ----------------
__global__ void k_conv_gate_ilv(const float* __restrict__ in, unsigned short* __restrict__ out) {
    int r = blockIdx.x;                   // 0..Gp-1
    int c = threadIdx.x * 4;
    ushort4 o;
    if (r < 2 * Fc) {
        int src = (r >> 1) + (r & 1) * Fc;
        float4 v = *(const float4*)(in + (size_t)src * Dc + c);
        o.x = f2b(v.x); o.y = f2b(v.y); o.z = f2b(v.z); o.w = f2b(v.w);
    } else {
        o.x = o.y = o.z = o.w = 0;
    }
    *(ushort4*)(out + (size_t)r * Dc + c) = o;
}

// ---------------- wout weight convert with col pad: [1024][Fc] -> [1024][Fp] ----------------
__global__ void k_conv_padk(const float* __restrict__ in, unsigned short* __restrict__ out) {
    int r = blockIdx.x;
    for (int c = threadIdx.x; c < Fp; c += 256) {
        float v = (c < Fc) ? in[(size_t)r * Fc + c] : 0.0f;
        out[(size_t)r * Fp + c] = f2b(v);
    }
}

// ---------------- me_norm -> bf16 out ----------------
__global__ void k_menorm_b(const float* __restrict__ x, const float* __restrict__ w,
                           unsigned short* __restrict__ out) {
    int row = blockIdx.x;
    float4 v = ((const float4*)(x + (size_t)row * Dc))[threadIdx.x];
    float s = fabsf(v.x) + fabsf(v.y) + fabsf(v.z) + fabsf(v.w);
#pragma unroll
    for (int m = 32; m >= 1; m >>= 1) s += __shfl_xor(s, m);
    __shared__ float ws4[4];
    if ((threadIdx.x & 63) == 0) ws4[threadIdx.x >> 6] = s;
    __syncthreads();
    float tot = ws4[0] + ws4[1] + ws4[2] + ws4[3];
    float inv = 1.0f / (tot / (float)Dc + EPSc);
    float4 wv = ((const float4*)w)[threadIdx.x];
    ushort4 o;
    o.x = f2b(v.x * inv * wv.x);
    o.y = f2b(v.y * inv * wv.y);
    o.z = f2b(v.z * inv * wv.z);
    o.w = f2b(v.w * inv * wv.w);
    ((ushort4*)(out + (size_t)row * Dc))[threadIdx.x] = o;
}

// ---------------- MFMA GEMM (m97 structure + XCD swizzle; BM = 64 or 128) ----------------
// Grid: (M/BM, N/128), bm from swizzled x. MODE 0: C = A@B^T (fp32). MODE 1: += Res.
// MODE 2: qkv fused epilogue -> U0=Qh,U1=Kh [bh][t][64], U2=Vt [bh][64][t] (bf16).
// MODE 3: gate fused epilogue -> U0 = g [2048][Fp] bf16 from interleaved cols.
template <int MODE, int BM>
__global__ __launch_bounds__(256) void k_mfma_gemm(
    const unsigned short* __restrict__ A, const unsigned short* __restrict__ Bw,
    const float* __restrict__ Res, float* __restrict__ C,
    unsigned short* __restrict__ U0, unsigned short* __restrict__ U1,
    unsigned short* __restrict__ U2, int N, int K) {
    constexpr int MFR = BM / 32;          // A-frags / acc rows per wave
    __shared__ __align__(16) unsigned short As[BM * 64];
    __shared__ __align__(16) unsigned short Bs[128 * 64];
    const int tid = threadIdx.x;
    const int lane = tid & 63;
    const int wid = tid >> 6;
    const int wr = wid >> 1, wc = wid & 1;
    const int l15 = lane & 15, g = lane >> 4;

    // XCD-aware swizzle (T1): all M-tiles of one B-panel -> same XCD. nwg % 8 == 0 here.
    const int nwg = gridDim.x * gridDim.y;
    int w = blockIdx.y * gridDim.x + blockIdx.x;
    int f = (nwg & 7) ? w : ((w & 7) * (nwg >> 3) + (w >> 3));
    const int bm = (f % gridDim.x) * BM, bn = (f / gridDim.x) * 128;

    f32x4 acc[MFR][4] = {};

    const int nk = K >> 6;
    for (int kt = 0; kt < nk; ++kt) {
        const int k0 = kt << 6;
#pragma unroll
        for (int it = 0; it < MFR; ++it) {
            int ci = it * 256 + tid;
            int r = ci >> 3;
            int sc = (ci & 7) ^ (r & 7);
            __builtin_amdgcn_global_load_lds(
                (const __attribute__((address_space(1))) void*)(A + (size_t)(bm + r) * K + k0 + sc * 8),
                (__attribute__((address_space(3))) void*)(As + ci * 8), 16, 0, 0);
        }
#pragma unroll
        for (int it = 0; it < 4; ++it) {
            int ci = it * 256 + tid;
            int r = ci >> 3;
            int sc = (ci & 7) ^ (r & 7);
            __builtin_amdgcn_global_load_lds(
                (const __attribute__((address_space(1))) void*)(Bw + (size_t)(bn + r) * K + k0 + sc * 8),
                (__attribute__((address_space(3))) void*)(Bs + ci * 8), 16, 0, 0);
        }
        __syncthreads();
#pragma unroll
        for (int kk = 0; kk < 2; ++kk) {
            bf16x8 af[MFR], bfr[4];
            const int kc = kk * 4 + g;
#pragma unroll
            for (int m = 0; m < MFR; ++m) {
                int row = wr * (BM / 2) + m * 16 + l15;
                af[m] = *(const bf16x8*)&As[(row * 8 + (kc ^ (row & 7))) * 8];
            }
#pragma unroll
            for (int n = 0; n < 4; ++n) {
                int col = wc * 64 + n * 16 + l15;
                bfr[n] = *(const bf16x8*)&Bs[(col * 8 + (kc ^ (col & 7))) * 8];
            }
#pragma unroll
            for (int m = 0; m < MFR; ++m)
#pragma unroll
                for (int n = 0; n < 4; ++n)
                    acc[m][n] = __builtin_amdgcn_mfma_f32_16x16x32_bf16(af[m], bfr[n], acc[m][n], 0, 0, 0);
        }
        __syncthreads();
    }

    // epilogue: C/D mapping col = lane&15, row = (lane>>4)*4 + j  [m89-verified]
#pragma unroll
    for (int m = 0; m < MFR; ++m) {
        int row0 = bm + wr * (BM / 2) + m * 16 + (g << 2);
#pragma unroll
        for (int n = 0; n < 4; ++n) {
            int col = bn + wc * 64 + n * 16 + l15;
            if constexpr (MODE == 0 || MODE == 1) {
#pragma unroll
                for (int j = 0; j < 4; ++j) {
                    size_t idx = (size_t)(row0 + j) * N + col;
                    float v = acc[m][n][j];
                    if (MODE == 1) v += Res[idx];
                    C[idx] = v;
                }
            } else if constexpr (MODE == 2) {
                if (col < 2048) {
                    unsigned short* dst = (col < 1024) ? U0 : U1;
                    int hh = (col & 1023) >> 6, dh = col & 63;
#pragma unroll
                    for (int j = 0; j < 4; ++j) {
                        int row = row0 + j;
                        int b = row >> 10, t = row & 1023;
                        dst[((size_t)((b * Hc + hh) * Tc + t)) * 64 + dh] = f2b(acc[m][n][j]);
                    }
                } else {
                    int hh = (col >> 6) & 15, dh = col & 63;
                    int b = row0 >> 10, t = row0 & 1023;
                    ushort4 o4;
                    o4.x = f2b(acc[m][n][0]); o4.y = f2b(acc[m][n][1]);
                    o4.z = f2b(acc[m][n][2]); o4.w = f2b(acc[m][n][3]);
                    *(ushort4*)&U2[((size_t)((b * Hc + hh) * 64 + dh)) * Tc + t] = o4;
                }
            } else {  // MODE 3: gate
                float pv[4];
#pragma unroll
                for (int j = 0; j < 4; ++j) pv[j] = __shfl_xor(acc[m][n][j], 1);
                if ((l15 & 1) == 0) {
                    int fq = col >> 1;
#pragma unroll
                    for (int j = 0; j < 4; ++j) {
                        float gate = acc[m][n][j], val = pv[j];
                        float sigma = 0.5f * (gate / (fabsf(gate) + 1.0f) + 1.0f);
                        U0[(size_t)(row0 + j) * Fp + fq] = f2b(gate * sigma * val);
                    }
                }
            }
        }
    }
}

// ---------------- 256x256 8-phase GEMM (T2+T3+T4+T5): C = A@B^T fp32 ----------------
// A [M][K] bf16, B [N][K] bf16. M%256==0, N%256==0, K%64==0. Grid (M/256, N/256), 512 thr.
// 8 waves (2M x 4N), per-wave 128x64 out. Double-buffered 128KB LDS, counted vmcnt(8).
__global__ __launch_bounds__(512, 2) void k_gemm_8ph(
    const unsigned short* __restrict__ A, const unsigned short* __restrict__ Bw,
    float* __restrict__ C, int N, int K) {
    __shared__ __align__(16) unsigned short As[2][256 * 64];
    __shared__ __align__(16) unsigned short Bs[2][256 * 64];
    const int tid = threadIdx.x;
    const int lane = tid & 63, wid = tid >> 6;
    const int wm = wid >> 2, wn = wid & 3;
    const int l15 = lane & 15, g = lane >> 4;

    const int nwg = gridDim.x * gridDim.y;
    int w = blockIdx.y * gridDim.x + blockIdx.x;
    int f = (nwg & 7) ? w : ((w & 7) * (nwg >> 3) + (w >> 3));
    const int bm = (f % gridDim.x) * 256;
    const int bn = (f / gridDim.x) * 256;

    const int nk = K >> 6;

    f32x4 acc[8][4] = {};

#define STAGE8(buf, kt)                                                                          \
    {                                                                                            \
        _Pragma("unroll") for (int it = 0; it < 4; ++it) {                                       \
            int ci = it * 512 + tid;                                                             \
            int r = ci >> 3, c = (ci & 7) ^ (r & 7);                                             \
            __builtin_amdgcn_global_load_lds(                                                    \
                (const __attribute__((address_space(1))) void*)(A + (size_t)(bm + r) * K + (kt) * 64 + c * 8), \
                (__attribute__((address_space(3))) void*)(&As[buf][ci * 8]), 16, 0, 0);          \
        }                                                                                        \
        _Pragma("unroll") for (int it = 0; it < 4; ++it) {                                       \
            int ci = it * 512 + tid;                                                             \
            int r = ci >> 3, c = (ci & 7) ^ (r & 7);                                             \
            __builtin_amdgcn_global_load_lds(                                                    \
                (const __attribute__((address_space(1))) void*)(Bw + (size_t)(bn + r) * K + (kt) * 64 + c * 8), \
                (__attribute__((address_space(3))) void*)(&Bs[buf][ci * 8]), 16, 0, 0);          \
        }                                                                                        \
    }

    STAGE8(0, 0);
    STAGE8(1, 1);
    asm volatile("s_waitcnt vmcnt(8)" ::: "memory");
    __builtin_amdgcn_s_barrier();

    for (int kt = 0; kt < nk; ++kt) {
        const int buf = kt & 1;
        const unsigned short* Ab = As[buf];
        const unsigned short* Bb = Bs[buf];
        bf16x8 bfr[4][2];
#pragma unroll
        for (int p = 0; p < 4; ++p) {
            bf16x8 af[2][2];
#pragma unroll
            for (int le = 0; le < 2; ++le) {
                int row = wm * 128 + (p * 2 + le) * 16 + l15;
#pragma unroll
                for (int kk = 0; kk < 2; ++kk) {
                    int kc = kk * 4 + g;
                    af[le][kk] = *(const bf16x8*)&Ab[(row * 8 + (kc ^ (row & 7))) * 8];
                }
            }
            if (p == 0) {
#pragma unroll
                for (int n = 0; n < 4; ++n) {
                    int col = wn * 64 + n * 16 + l15;
#pragma unroll
                    for (int kk = 0; kk < 2; ++kk) {
                        int kc = kk * 4 + g;
                        bfr[n][kk] = *(const bf16x8*)&Bb[(col * 8 + (kc ^ (col & 7))) * 8];
                    }
                }
            }
            __builtin_amdgcn_s_barrier();          // all waves done this phase's LDS reads
            if (p == 3 && kt + 2 < nk) STAGE8(buf, kt + 2);  // buf fully read -> restage
            __builtin_amdgcn_s_setprio(1);
#pragma unroll
            for (int kk = 0; kk < 2; ++kk)
#pragma unroll
                for (int le = 0; le < 2; ++le)
#pragma unroll
                    for (int n = 0; n < 4; ++n)
                        acc[p * 2 + le][n] = __builtin_amdgcn_mfma_f32_16x16x32_bf16(
                            af[le][kk], bfr[n][kk], acc[p * 2 + le][n], 0, 0, 0);
            __builtin_amdgcn_s_setprio(0);
            if (p == 3) {
                if (kt + 2 < nk) {
                    asm volatile("s_waitcnt vmcnt(8)" ::: "memory");   // prev tile landed
                } else {
                    asm volatile("s_waitcnt vmcnt(0)" ::: "memory");   // tail drain
                }
            }
            __builtin_amdgcn_s_barrier();
        }
    }
#undef STAGE8

    // epilogue: C/D mapping col = lane&15, row = (lane>>4)*4 + j
#pragma unroll
    for (int m = 0; m < 8; ++m) {
        int row0 = bm + wm * 128 + m * 16 + (g << 2);
#pragma unroll
        for (int n = 0; n < 4; ++n) {
            int col = bn + wn * 64 + n * 16 + l15;
#pragma unroll
            for (int j = 0; j < 4; ++j)
                C[(size_t)(row0 + j) * N + col] = acc[m][n][j];
        }
    }
}

// ---------------- MFMA attention: block = (b, h, 64 q-rows), 4 waves x 16 rows ----------------
__global__ __launch_bounds__(256) void k_attn_mfma(
    const unsigned short* __restrict__ Qh, const unsigned short* __restrict__ Kh,
    const unsigned short* __restrict__ Vt, unsigned short* __restrict__ o) {
    const int q0 = blockIdx.x * 64;
    const int h = blockIdx.y, b = blockIdx.z;
    const int bh = b * Hc + h;
    const float slope = exp2f(-0.5f * (float)(h + 1));

    __shared__ __align__(16) unsigned short Ks[64 * 64];
    __shared__ __align__(16) unsigned short Vs[64 * 64];
    __shared__ __align__(16) unsigned short Ps[4][16 * 64];

    const int tid = threadIdx.x, lane = tid & 63, wid = tid >> 6;
    const int q0w = q0 + wid * 16;
    const int l15 = lane & 15, g = lane >> 4;

    const unsigned short* qbase = Qh + ((size_t)(bh * Tc + q0w + l15)) * 64 + g * 8;
    bf16x8 qf[2];
    qf[0] = *(const bf16x8*)qbase;
    qf[1] = *(const bf16x8*)(qbase + 32);

    const int nt = q0 / 64 + 1;

    // ---------- pass A: exact row max ----------
    f32x4 mx = {-3e38f, -3e38f, -3e38f, -3e38f};
    for (int it = 0; it < nt; ++it) {
        const int st = it * 64;
        __syncthreads();
#pragma unroll
        for (int half = 0; half < 2; ++half) {
            int ci = half * 256 + tid;
            int r = ci >> 3, sc = (ci & 7) ^ (r & 7);
            __builtin_amdgcn_global_load_lds(
                (const __attribute__((address_space(1))) void*)(Kh + ((size_t)(bh * Tc + st + r)) * 64 + sc * 8),
                (__attribute__((address_space(3))) void*)(Ks + ci * 8), 16, 0, 0);
        }
        __syncthreads();
#pragma unroll
        for (int si = 0; si < 4; ++si) {
            f32x4 d = {0.f, 0.f, 0.f, 0.f};
#pragma unroll
            for (int kc = 0; kc < 2; ++kc) {
                int r2 = si * 16 + l15;
                int c2 = kc * 4 + g;
                bf16x8 bk = *(const bf16x8*)&Ks[(r2 * 8 + (c2 ^ (r2 & 7))) * 8];
                d = __builtin_amdgcn_mfma_f32_16x16x32_bf16(qf[kc], bk, d, 0, 0, 0);
            }
            int s = st + si * 16 + l15;
#pragma unroll
            for (int j = 0; j < 4; ++j) {
                int t = q0w + g * 4 + j;
                float scv = (s <= t) ? d[j] * SCALEc - slope * (float)(t - s) : -3e38f;
                mx[j] = fmaxf(mx[j], scv);
            }
        }
    }
#pragma unroll
    for (int m = 8; m >= 1; m >>= 1)
#pragma unroll
        for (int j = 0; j < 4; ++j) mx[j] = fmaxf(mx[j], __shfl_xor(mx[j], m));

    // ---------- pass B: numerators, sum, PV ----------
    f32x4 sum = {0.f, 0.f, 0.f, 0.f};
    f32x4 oacc[4] = {};
    for (int it = 0; it < nt; ++it) {
        const int st = it * 64;
        __syncthreads();
#pragma unroll
        for (int half = 0; half < 2; ++half) {
            int ci = half * 256 + tid;
            int r = ci >> 3, sc = (ci & 7) ^ (r & 7);
            __builtin_amdgcn_global_load_lds(
                (const __attribute__((address_space(1))) void*)(Kh + ((size_t)(bh * Tc + st + r)) * 64 + sc * 8),
                (__attribute__((address_space(3))) void*)(Ks + ci * 8), 16, 0, 0);
            __builtin_amdgcn_global_load_lds(
                (const __attribute__((address_space(1))) void*)(Vt + ((size_t)(bh * 64 + r)) * Tc + st + sc * 8),
                (__attribute__((address_space(3))) void*)(Vs + ci * 8), 16, 0, 0);
        }
        __syncthreads();
#pragma unroll
        for (int si = 0; si < 4; ++si) {
            f32x4 d = {0.f, 0.f, 0.f, 0.f};
#pragma unroll
            for (int kc = 0; kc < 2; ++kc) {
                int r2 = si * 16 + l15;
                int c2 = kc * 4 + g;
                bf16x8 bk = *(const bf16x8*)&Ks[(r2 * 8 + (c2 ^ (r2 & 7))) * 8];
                d = __builtin_amdgcn_mfma_f32_16x16x32_bf16(qf[kc], bk, d, 0, 0, 0);
            }
            int sl = si * 16 + l15;
            int s = st + sl;
            int chunk = sl >> 3, coff = sl & 7;
#pragma unroll
            for (int j = 0; j < 4; ++j) {
                int t = q0w + g * 4 + j;
                int q = g * 4 + j;
                unsigned short pb = 0;
                if (s <= t) {
                    float sv = d[j] * SCALEc - slope * (float)(t - s) - mx[j];
                    float num = __builtin_amdgcn_rcpf(fmaf(0.5f * sv, sv, 1.0f - sv));
                    sum[j] += num;
                    pb = f2b(num);
                }
                Ps[wid][q * 64 + ((chunk ^ (q & 7)) * 8) + coff] = pb;
            }
        }
        __syncthreads();
#pragma unroll
        for (int kc = 0; kc < 2; ++kc) {
            int c2 = kc * 4 + g;
            bf16x8 pa = *(const bf16x8*)&Ps[wid][(l15 * 8 + (c2 ^ (l15 & 7))) * 8];
#pragma unroll
            for (int n = 0; n < 4; ++n) {
                int r2 = n * 16 + l15;
                bf16x8 vb = *(const bf16x8*)&Vs[(r2 * 8 + (c2 ^ (r2 & 7))) * 8];
                oacc[n] = __builtin_amdgcn_mfma_f32_16x16x32_bf16(pa, vb, oacc[n], 0, 0, 0);
            }
        }
    }
#pragma unroll
    for (int m = 8; m >= 1; m >>= 1)
#pragma unroll
        for (int j = 0; j < 4; ++j) sum[j] += __shfl_xor(sum[j], m);

#pragma unroll
    for (int j = 0; j < 4; ++j) {
        int t = q0w + g * 4 + j;
        float svm = NEGc - mx[j];
        float mnum = __builtin_amdgcn_rcpf(fmaf(0.5f * svm, svm, 1.0f - svm));
        float inv = __builtin_amdgcn_rcpf(sum[j] + (float)(Tc - 1 - t) * mnum + EPSc);
#pragma unroll
        for (int n = 0; n < 4; ++n) {
            o[((size_t)(b * Tc + t)) * Dc + h * 64 + n * 16 + l15] = f2b(oacc[n][j] * inv);
        }
    }
}

extern "C" void kernel_launch(void* const* d_in, const int* in_sizes, int n_in,
                              void* d_out, int out_size, void* d_ws, size_t ws_size,
                              hipStream_t stream) {
    const int* ids = (const int*)d_in[0];
    const float* embed_w = (const float*)d_in[1];
    const float* qkv_w = (const float*)d_in[2];
    const float* out_w = (const float*)d_in[3];
    const float* gate_w = (const float*)d_in[4];
    const float* wout_w = (const float*)d_in[5];
    const float* n1 = (const float*)d_in[6];
    const float* n2 = (const float*)d_in[7];
    const float* nf = (const float*)d_in[8];
    float* outp = (float*)d_out;

    char* ws = (char*)d_ws;
    float* x = (float*)(ws + 0);                                   //  8,388,608
    unsigned short* h = (unsigned short*)(ws + 8388608);           //  4,194,304 (h / o share)
    unsigned short* Qh = (unsigned short*)(ws + 12582912);         //  4,194,304
    unsigned short* Kh = (unsigned short*)(ws + 16777216);         //  4,194,304
    unsigned short* Vt = (unsigned short*)(ws + 20971520);         //  4,194,304
    unsigned short* g = (unsigned short*)(ws + 25165824);          // 11,272,192
    unsigned short* w1 = (unsigned short*)(ws + 36438016);         //  6,291,456 (wq / ww share)
    unsigned short* wo_b = (unsigned short*)(ws + 42729472);       //  2,097,152
    unsigned short* wg_b = (unsigned short*)(ws + 44826624);       // 11,272,192 (end 56,098,816)
    unsigned short* emb_b = (unsigned short*)(ws + 12582912);      // 65,536,000 overlay (end 78,118,912)

    dim3 blk(256);

    k_embed<<<dim3(Mc), blk, 0, stream>>>(ids, embed_w, x);

    for (int l = 0; l < 4; l++) {
        const float* wq = qkv_w + (size_t)l * 3 * Dc * Dc;
        const float* wo = out_w + (size_t)l * Dc * Dc;
        const float* wg = gate_w + (size_t)l * 2 * Fc * Dc;
        const float* ww = wout_w + (size_t)l * Dc * Fc;

        k_conv<<<dim3(3072), blk, 0, stream>>>(wq, w1);
        k_conv<<<dim3(1024), blk, 0, stream>>>(wo, wo_b);
        k_conv_gate_ilv<<<dim3(Gp), blk, 0, stream>>>(wg, wg_b);

        // h = me_norm(x, n1) -> bf16
        k_menorm_b<<<dim3(Mc), blk, 0, stream>>>(x, n1 + (size_t)l * Dc, h);
        // qkv GEMM fused: writes Qh, Kh, Vt directly (N=3072, K=1024)
        k_mfma_gemm<2, 128><<<dim3(16, 24), blk, 0, stream>>>(h, w1, nullptr, nullptr, Qh, Kh, Vt, 3 * Dc, Dc);
        // ww -> w1 (wq no longer needed)
        k_conv_padk<<<dim3(1024), blk, 0, stream>>>(ww, w1);
        // attention -> o (bf16, into h buffer)
        k_attn_mfma<<<dim3(Tc / 64, Hc, Bc), blk, 0, stream>>>(Qh, Kh, Vt, h);
        // x = x + o @ wo^T  (N=1024, K=1024), BM=64 -> 256 wgs
        k_mfma_gemm<1, 64><<<dim3(32, 8), blk, 0, stream>>>(h, wo_b, x, x, nullptr, nullptr, nullptr, Dc, Dc);
        // h = me_norm(x, n2)
        k_menorm_b<<<dim3(Mc), blk, 0, stream>>>(x, n2 + (size_t)l * Dc, h);
        // gate GEMM fused: g = gate*sigma*val bf16 (N=5504 interleaved, K=1024)
        k_mfma_gemm<3, 128><<<dim3(16, Gp / 128), blk, 0, stream>>>(h, wg_b, nullptr, nullptr, g, nullptr, nullptr, Gp, Dc);
        // x = x + g @ ww^T  (N=1024, K=2752 padded), BM=64 -> 256 wgs
        k_mfma_gemm<1, 64><<<dim3(32, 8), blk, 0, stream>>>(g, w1, x, x, nullptr, nullptr, nullptr, Dc, Fp);
    }

    // final norm + logits
    k_menorm_b<<<dim3(Mc), blk, 0, stream>>>(x, nf, h);
    k_conv<<<dim3(32000), blk, 0, stream>>>(embed_w, emb_b);
    // logits = h @ embed^T  (N=32000, K=1024) — 256^2 8-phase kernel
    k_gemm_8ph<<<dim3(8, 125), dim3(512), 0, stream>>>(h, emb_b, outp, 32000, Dc);
}